// Round 2
// baseline (383.701 us; speedup 1.0000x reference)
//
#include <hip/hip_runtime.h>
#include <cstdint>
#include <cmath>

#define NB 256      // graphs (B)
#define MM 256      // nodes per graph
#define NN (NB*MM)  // 65536 nodes
#define KNN 15
#define FIN 7
#define CC 128
#define CCP 152     // padded LDS row stride (shorts): 304B = 76 dwords == 12 (mod 32).
                    // Row stride must be ==0 mod 8 shorts (b128 align), so row starts
                    // are pinned to 4-dword bank residues; 152 is the best of that
                    // family for MFMA A-frag reads (R12-16: 136 gave 4-way, 3.02M).
#define C2 768
#define NL 3
#define FINF 3.4e38f

__device__ __forceinline__ float lrelu(float v){ return v > 0.f ? v : 0.01f*v; }

__device__ __forceinline__ unsigned short f2bf(float f){
  unsigned u = __float_as_uint(f);
  return (unsigned short)((u + 0x7FFFu + ((u >> 16) & 1u)) >> 16);
}
__device__ __forceinline__ float bf2f(unsigned short h){
  return __uint_as_float(((unsigned)h) << 16);
}

__device__ __forceinline__ int mbcnt64(unsigned long long m){
  return (int)__builtin_amdgcn_mbcnt_hi((unsigned)(m >> 32),
              __builtin_amdgcn_mbcnt_lo((unsigned)m, 0u));
}

typedef short bf16x8 __attribute__((ext_vector_type(8)));
typedef float f32x4  __attribute__((ext_vector_type(4)));
typedef float f32x2  __attribute__((ext_vector_type(2)));

// ------------------------------------------- kNN + packW (merged dispatch) --
// Radix-select (R9: 143 -> 58 us). Parked: issue/SALU-bound, micro-variants
// neutral (R8) or negative (R4, R15-split). packW (384 trivial blocks) rides
// along in the same grid to save one dispatch gap.
__global__ __launch_bounds__(256) void knnpack_kernel(
    const float* __restrict__ x, int* __restrict__ knn,
    const float* __restrict__ W2src, const float* __restrict__ W3src,
    unsigned short* __restrict__ W2dst, unsigned short* __restrict__ W3dst){
  __shared__ float4 pos[MM];
  __shared__ float  sq[MM];
  __shared__ unsigned skey[4][16];
  __shared__ int      sidx[4][16];

  if (blockIdx.x >= NB*64){
    // ---- packW path: pack W into MFMA B-frag order ----
    int idx = (blockIdx.x - NB*64)*256 + threadIdx.x;
    if (idx < 2*3*CC*CC){
      const float* Wsrc = (idx < 3*CC*CC) ? W2src : W3src;
      unsigned short* Wdst = (idx < 3*CC*CC) ? W2dst : W3dst;
      int e = (idx < 3*CC*CC) ? idx : idx - 3*CC*CC;
      int kg = e >> 7;
      int nn = e & 127;
      int ck = kg >> 5, q = (kg >> 3) & 3, j = kg & 7;
      Wdst[(((ck*4 + q)*CC) + nn)*8 + j] = f2bf(Wsrc[e]);
    }
    return;
  }

  const int g = blockIdx.x >> 6;
  const int t = threadIdx.x;
  const float* xr = x + (size_t)(g*MM + t)*FIN;
  float4 p = make_float4(xr[0], xr[1], xr[2], xr[3]);
  pos[t] = p;
  sq[t]  = p.x*p.x + p.y*p.y + p.z*p.z + p.w*p.w;
  __syncthreads();

  const int i    = (blockIdx.x & 63)*4 + (t >> 6);
  const int wv   = t >> 6;
  const int lane = t & 63;
  const float4 pi = pos[i];
  const float  sqi = sq[i];

  unsigned key[4];
#pragma unroll
  for (int qq=0;qq<4;qq++){
    int j = qq*64 + lane;
    float4 pj = pos[j];
    float dot = pi.x*pj.x + pi.y*pj.y + pi.z*pj.z + pi.w*pj.w;
    float d2  = sqi + sq[j] - 2.f*dot;
    unsigned u = __float_as_uint(d2);
    u = ((int)u < 0) ? ~u : (u ^ 0x80000000u);
    key[qq] = (j == i) ? 0xFFFFFFFFu : u;
  }

  unsigned prefix = 0u;
#pragma unroll
  for (int bit=31; bit>=0; --bit){
    unsigned trial = prefix | (1u << bit);
    int c = __popcll(__ballot(key[0] < trial))
          + __popcll(__ballot(key[1] < trial))
          + __popcll(__ballot(key[2] < trial))
          + __popcll(__ballot(key[3] < trial));
    if (c < KNN) prefix = trial;
  }
  const unsigned K = prefix;

  int c_lt = __popcll(__ballot(key[0] < K)) + __popcll(__ballot(key[1] < K))
           + __popcll(__ballot(key[2] < K)) + __popcll(__ballot(key[3] < K));
  int need = KNN - c_lt;
  bool w[4];
  int eqbase = 0;
#pragma unroll
  for (int qq=0;qq<4;qq++){
    unsigned long long em = __ballot(key[qq] == K);
    int gr = eqbase + mbcnt64(em);
    w[qq] = (key[qq] < K) || ((key[qq] == K) && (gr < need));
    eqbase += __popcll(em);
  }

  int base2 = 0;
#pragma unroll
  for (int qq=0;qq<4;qq++){
    unsigned long long wm = __ballot(w[qq]);
    int rk = mbcnt64(wm);
    if (w[qq]){ skey[wv][base2+rk] = key[qq]; sidx[wv][base2+rk] = qq*64 + lane; }
    base2 += __popcll(wm);
  }
  __builtin_amdgcn_wave_barrier();

  if (lane < KNN){
    unsigned mk = skey[wv][lane]; int mi = sidx[wv][lane];
    int r = 0;
#pragma unroll
    for (int m=0;m<KNN;m++){
      unsigned ok = skey[wv][m]; int oi = sidx[wv][m];
      r += (ok < mk || (ok == mk && oi < mi)) ? 1 : 0;
    }
    knn[(size_t)(g*MM + i)*KNN + r] = g*MM + mi;
  }
}

// --------------------------------------------------------- conv helpers -----
// one neighbor-row accumulate (bit-exact unpack order: lo then hi per dword)
__device__ __forceinline__ void agg_accum(const unsigned short* __restrict__ src,
                                          int off,
                                          f32x2& s0, f32x2& s1, f32x2& s2, f32x2& s3){
  uint4 r = *(const uint4*)(src + off);
  f32x2 v;
  v[0] = __uint_as_float(r.x << 16); v[1] = __uint_as_float(r.x & 0xFFFF0000u); s0 += v;
  v[0] = __uint_as_float(r.y << 16); v[1] = __uint_as_float(r.y & 0xFFFF0000u); s1 += v;
  v[0] = __uint_as_float(r.z << 16); v[1] = __uint_as_float(r.z & 0xFFFF0000u); s2 += v;
  v[0] = __uint_as_float(r.w << 16); v[1] = __uint_as_float(r.w & 0xFFFF0000u); s3 += v;
}

// one agg work-item: 15 gathers + 1/15 scale + bf16 pack + store (verbatim math)
__device__ __forceinline__ void agg_iter(const unsigned short* __restrict__ src,
                                         unsigned short* __restrict__ dst,
                                         const unsigned* __restrict__ opk8,
                                         int rowoff, int c8){
  f32x2 s0 = {0.f,0.f}, s1 = {0.f,0.f}, s2 = {0.f,0.f}, s3 = {0.f,0.f};
#pragma unroll
  for (int kk=0; kk<7; ++kk){
    unsigned pk = opk8[kk];
    agg_accum(src, (int)(pk & 0xFFFFu) + c8, s0, s1, s2, s3);
    agg_accum(src, (int)(pk >> 16)    + c8, s0, s1, s2, s3);
  }
  agg_accum(src, (int)(opk8[7] & 0xFFFFu) + c8, s0, s1, s2, s3);
  const float inv = 1.f/15.f;
  uint4 o;
  o.x = (unsigned)f2bf(s0[0]*inv) | ((unsigned)f2bf(s0[1]*inv) << 16);
  o.y = (unsigned)f2bf(s1[0]*inv) | ((unsigned)f2bf(s1[1]*inv) << 16);
  o.z = (unsigned)f2bf(s2[0]*inv) | ((unsigned)f2bf(s2[1]*inv) << 16);
  o.w = (unsigned)f2bf(s3[0]*inv) | ((unsigned)f2bf(s3[1]*inv) << 16);
  *(uint4*)(dst + rowoff + c8) = o;
}

// one MFMA K-chunk (order-preserving: identical to old mfma_seg inner body)
__device__ __forceinline__ void mfma_chunk(const unsigned short* __restrict__ A,
                                           const unsigned short* __restrict__ Wpk,
                                           int ck, int rows0, int cols0,
                                           int n, int q, f32x4 (&acc)[2][4]){
  const int kc = ck & 3;
  const unsigned short* ab = A + (rows0 + n)*CCP + kc*32 + q*8;
  bf16x8 af[2];
#pragma unroll
  for (int i=0;i<2;i++) af[i] = *(const bf16x8*)(ab + i*16*CCP);
  const unsigned short* wb = Wpk + ((size_t)(ck*4 + q)*CC + cols0 + n)*8;
  bf16x8 bfr[4];
#pragma unroll
  for (int t=0;t<4;t++) bfr[t] = *(const bf16x8*)(wb + t*16*8);
#pragma unroll
  for (int i=0;i<2;i++)
#pragma unroll
    for (int t=0;t<4;t++)
      acc[i][t] = __builtin_amdgcn_mfma_f32_16x16x32_bf16(af[i], bfr[t], acc[i][t], 0, 0, 0);
}

__device__ __forceinline__ void conv_epilogue(const float* __restrict__ bvec,
                                              f32x4 (&acc)[2][4],
                                              unsigned short* __restrict__ dst,
                                              int rows0, int cols0, int n, int q){
  float bv[4];
#pragma unroll
  for (int t=0;t<4;t++) bv[t] = bvec[cols0 + t*16 + n];
#pragma unroll
  for (int i=0;i<2;i++)
#pragma unroll
    for (int t=0;t<4;t++)
#pragma unroll
      for (int r=0;r<4;r++){
        int row = rows0 + i*16 + q*4 + r;
        int col = cols0 + t*16 + n;
        dst[row*CCP + col] = f2bf(lrelu(acc[i][t][r] + bv[t]));
      }
}

// all-wave pool: waves 0-7 sum, waves 8-15 max (same add/max order as before
// -> bit-exact; doubles thread utilization of the pool phase). NOTE: no
// trailing barrier -- callers rely on: next phase never reads pool's scratch,
// never writes pool's source buffer before the next full barrier.
__device__ __forceinline__ void pool_block(const unsigned short* __restrict__ buf,
                                           float* __restrict__ gf_base,
                                           float (*smean)[CC], float (*smax)[CC],
                                           int tid){
  const int c = tid & 127;
  const int grp = tid >> 7;             // 0..7, wave-uniform
  if (grp < 4){
    float s = 0.f;
    for (int m=grp*64; m<grp*64+64; ++m) s += bf2f(buf[m*CCP + c]);
    smean[grp][c] = s;
  } else {
    const int gg = grp - 4;
    float mx = -FINF;
    for (int m=gg*64; m<gg*64+64; ++m) mx = fmaxf(mx, bf2f(buf[m*CCP + c]));
    smax[gg][c] = mx;
  }
  __syncthreads();
  if (tid < 128){
    gf_base[c] = (smean[0][c] + smean[1][c] + smean[2][c] + smean[3][c]) * (1.f/MM);
  } else if (tid < 256){
    gf_base[CC + c] = fmaxf(fmaxf(smax[0][c], smax[1][c]),
                            fmaxf(smax[2][c], smax[3][c]));
  }
}

// ---------------- conv layers 1+2+3 fully fused (one block per graph) -------
// Layer 1 (feat agg7 x2 + conv1) runs inside this kernel: h never touches
// global. Layers 2/3: MFMA chunks interleaved 1:1 with agg iterations --
// phase A reads bufX for BOTH agg-src and MFMA A-frags and writes only bufY,
// so no intra-phase hazard; barriers and MFMA accumulation order unchanged
// -> bit-exact. Neighbor offsets preloaded once (u16-packed, 32 VGPRs).
// LDS: 2 x 76.0 KB bufs + 4 KB pool scratch = 156.0 KB -> 1 block/CU,
// 4 waves/SIMD, LDS-bound. __launch_bounds__(1024, 4) declares exactly that
// occupancy, unlocking the full 512/4 = 128-VGPR budget. R1 lesson: the
// default cap (64 VGPR for 8-waves/SIMD occupancy that LDS makes unreachable)
// spilled the ~110-reg live set to scratch: 187 MB phantom WRITE_SIZE,
// 135 us. Persistent state: acc 32 + opk 32; phase working set ~45.
__global__ __launch_bounds__(1024, 4) void conv_all_kernel(
    const float* __restrict__ x,
    const int* __restrict__ knn,
    const float* __restrict__ Wc1, const float* __restrict__ bc1,
    const unsigned short* __restrict__ Wpk2, const float* __restrict__ b2,
    const unsigned short* __restrict__ Wpk3, const float* __restrict__ b3,
    float* __restrict__ gf){
  __shared__ __align__(16) unsigned short bufh[MM*CCP];   // 77824 B
  __shared__ __align__(16) unsigned short bufa[MM*CCP];   // 77824 B
  __shared__ float smean[4][CC], smax[4][CC];
  const int g   = blockIdx.x;
  const int tid = threadIdx.x;
  const int* kn_graph = knn + (size_t)g*MM*KNN;

  // ---- preload agg neighbor offsets (loc*CCP, u16-packed; same lists feed
  // all 4 agg calls of layers 2 and 3) ----
  const int nbase = tid >> 4;
  const int c8    = (tid & 15) * 8;
  unsigned opk[4][8];
#pragma unroll
  for (int it=0; it<4; ++it){
    const int* kn = kn_graph + (it*64 + nbase)*KNN;
#pragma unroll
    for (int kk=0; kk<8; ++kk){
      unsigned lo = (unsigned)((kn[2*kk] & (MM-1)) * CCP);
      unsigned hi = (kk < 7) ? (unsigned)((kn[2*kk+1] & (MM-1)) * CCP) : 0u;
      opk[it][kk] = lo | (hi << 16);
    }
  }

  // ================= layer 1 (feat in bufa's space) =================
  {
    float (*feat)[24] = (float (*)[24])bufa;    // 24576 B < bufa
    for (int e=tid; e<MM*FIN; e+=1024){
      int nn = e / FIN, f = e - nn*FIN;
      feat[nn][f] = x[(size_t)g*MM*FIN + e];
    }
    __syncthreads();
    const bool active = tid < MM;
    int loc[KNN];
    if (active){
      const int* kn = kn_graph + tid*KNN;
#pragma unroll
      for (int k=0;k<KNN;k++) loc[k] = kn[k] & (MM-1);
#pragma unroll
      for (int c=0;c<FIN;c++){
        float s = 0.f;
#pragma unroll
        for (int k=0;k<KNN;k++) s += feat[loc[k]][c];
        feat[tid][FIN + c] = s * (1.f/15.f);
      }
    }
    __syncthreads();
    if (active){
#pragma unroll
      for (int c=0;c<FIN;c++){
        float s = 0.f;
#pragma unroll
        for (int k=0;k<KNN;k++) s += feat[loc[k]][FIN + c];
        feat[tid][2*FIN + c] = s * (1.f/15.f);
      }
    }
    __syncthreads();
    // conv1: 1024 threads, 8 segs x 32 nodes; write h into bufh (CCP layout)
    {
      const int cc_ = tid & 127;
      const int seg = tid >> 7;
      float wcol[3*FIN];
#pragma unroll
      for (int t2=0;t2<3*FIN;t2++) wcol[t2] = Wc1[t2*CC + cc_];
      const float bc = bc1[cc_];
      for (int nn=seg*32; nn<seg*32+32; ++nn){
        float4 f0 = *(const float4*)(&feat[nn][0]);
        float4 f1 = *(const float4*)(&feat[nn][4]);
        float4 f2 = *(const float4*)(&feat[nn][8]);
        float4 f3 = *(const float4*)(&feat[nn][12]);
        float4 f4 = *(const float4*)(&feat[nn][16]);
        float4 f5 = *(const float4*)(&feat[nn][20]);
        float fv[21] = {f0.x,f0.y,f0.z,f0.w, f1.x,f1.y,f1.z,f1.w,
                        f2.x,f2.y,f2.z,f2.w, f3.x,f3.y,f3.z,f3.w,
                        f4.x,f4.y,f4.z,f4.w, f5.x};
        float a1 = bc;
#pragma unroll
        for (int t2=0;t2<3*FIN;t2++) a1 += fv[t2]*wcol[t2];
        bufh[nn*CCP + cc_] = f2bf(lrelu(a1));
      }
    }
    __syncthreads();
    pool_block(bufh, gf + (size_t)g*C2, smean, smax, tid);
    // no barrier: phase A2 reads bufh (read-read with pool partials) and
    // writes only bufa (feat now dead); pool finals touch only smean/smax.
  }

  const int wv   = tid >> 6, lane = tid & 63;
  const int n    = lane & 15, q = lane >> 4;
  const int rows0 = (wv & 7)*32;
  const int cols0 = (wv >> 3)*64;

  f32x4 acc[2][4];

  // ================= layer 2 =================
#pragma unroll
  for (int i=0;i<2;i++)
#pragma unroll
    for (int t=0;t<4;t++) acc[i][t] = (f32x4){0.f,0.f,0.f,0.f};
  // phase A: mfma(bufh ck0-3) interleaved with a1_2 = agg(bufh) -> bufa
#pragma unroll
  for (int it=0; it<4; ++it){
    mfma_chunk(bufh, Wpk2, it, rows0, cols0, n, q, acc);
    agg_iter(bufh, bufa, opk[it], (it*64 + nbase)*CCP, c8);
  }
  __syncthreads();
  // phase B: mfma(bufa ck4-7) interleaved with a2_2 = agg(bufa) -> bufh
#pragma unroll
  for (int it=0; it<4; ++it){
    mfma_chunk(bufa, Wpk2, 4+it, rows0, cols0, n, q, acc);
    agg_iter(bufa, bufh, opk[it], (it*64 + nbase)*CCP, c8);
  }
  __syncthreads();
  // phase C: mfma(bufh ck8-11) + epilogue -> bufa (h3 stays in LDS)
#pragma unroll
  for (int cki=0; cki<4; ++cki)
    mfma_chunk(bufh, Wpk2, 8+cki, rows0, cols0, n, q, acc);
  conv_epilogue(b2, acc, bufa, rows0, cols0, n, q);
  __syncthreads();
  pool_block(bufa, gf + (size_t)g*C2 + 2*CC, smean, smax, tid);
  // no barrier: phase A3 reads bufa (read-read with pool) and writes bufh.

  // ================= layer 3 (h3 = bufa) =================
#pragma unroll
  for (int i=0;i<2;i++)
#pragma unroll
    for (int t=0;t<4;t++) acc[i][t] = (f32x4){0.f,0.f,0.f,0.f};
#pragma unroll
  for (int it=0; it<4; ++it){
    mfma_chunk(bufa, Wpk3, it, rows0, cols0, n, q, acc);
    agg_iter(bufa, bufh, opk[it], (it*64 + nbase)*CCP, c8);
  }
  __syncthreads();
#pragma unroll
  for (int it=0; it<4; ++it){
    mfma_chunk(bufh, Wpk3, 4+it, rows0, cols0, n, q, acc);
    agg_iter(bufh, bufa, opk[it], (it*64 + nbase)*CCP, c8);
  }
  __syncthreads();
#pragma unroll
  for (int cki=0; cki<4; ++cki)
    mfma_chunk(bufa, Wpk3, 8+cki, rows0, cols0, n, q, acc);
  conv_epilogue(b3, acc, bufh, rows0, cols0, n, q);
  __syncthreads();
  pool_block(bufh, gf + (size_t)g*C2 + 4*CC, smean, smax, tid);
}

// ------------------------------------------------------ batchnorm (stats) ---
__global__ __launch_bounds__(256) void bnstats_kernel(const float* __restrict__ g,
                                                      const float* __restrict__ gamma,
                                                      const float* __restrict__ beta,
                                                      float* __restrict__ scb,
                                                      float* __restrict__ shb){
  __shared__ float ssum[4][64], ssq[4][64];
  const int cl = threadIdx.x & 63, rg = threadIdx.x >> 6;
  const int c  = blockIdx.x*64 + cl;
  float s=0.f, q=0.f;
  for (int r=rg*64; r<rg*64+64; r++){
    float v = g[(size_t)r*C2 + c];
    s += v; q += v*v;
  }
  ssum[rg][cl]=s; ssq[rg][cl]=q;
  __syncthreads();
  if (rg == 0){
    s = ssum[0][cl]+ssum[1][cl]+ssum[2][cl]+ssum[3][cl];
    q = ssq [0][cl]+ssq [1][cl]+ssq [2][cl]+ssq [3][cl];
    float mu  = s * (1.f/NB);
    float var = q * (1.f/NB) - mu*mu;
    float sc  = rsqrtf(var + 1e-5f) * gamma[c];
    scb[c] = sc;
    shb[c] = beta[c] - mu*sc;
  }
}

// -------------------------------------------------- MLP (wave-K-split GEMM) -
__global__ __launch_bounds__(512) void mlp_gemm_kernel(
    const float* __restrict__ A, const float* __restrict__ W,
    const float* __restrict__ bias,
    const float* __restrict__ scb, const float* __restrict__ shb, int affine,
    float* __restrict__ out){
  __shared__ float Ws[8][32][64];   // 64 KB
  __shared__ float At[8][32][10];   // 10 KB
  const int tid  = threadIdx.x;
  const int ks   = tid >> 6, lane = tid & 63;
  const int colq = lane & 15, rp = lane >> 4;
  const int col0 = blockIdx.x * 64;
  const int row0 = blockIdx.y * 8;

  float a00=0.f,a01=0.f,a02=0.f,a03=0.f;
  float a10=0.f,a11=0.f,a12=0.f,a13=0.f;

  for (int kt=0; kt<3; kt++){
    const int kc0 = ks*96 + kt*32;
#pragma unroll
    for (int i=0;i<8;i++){
      int idx = i*256 + lane*4;
      int kr = idx >> 6, cc = idx & 63;
      *(float4*)(&Ws[ks][kr][cc]) =
          *(const float4*)(W + (size_t)(kc0+kr)*C2 + col0 + cc);
    }
    {
      int row = lane >> 3, kq = lane & 7;
      float4 a = *(const float4*)(A + (size_t)(row0+row)*C2 + kc0 + kq*4);
      if (affine){
        float4 s4 = *(const float4*)(scb + kc0 + kq*4);
        float4 h4 = *(const float4*)(shb + kc0 + kq*4);
        a.x = a.x*s4.x + h4.x; a.y = a.y*s4.y + h4.y;
        a.z = a.z*s4.z + h4.z; a.w = a.w*s4.w + h4.w;
      }
      At[ks][kq*4+0][row] = a.x;
      At[ks][kq*4+1][row] = a.y;
      At[ks][kq*4+2][row] = a.z;
      At[ks][kq*4+3][row] = a.w;
    }
    __builtin_amdgcn_wave_barrier();
#pragma unroll 8
    for (int kk=0;kk<32;kk++){
      float4 w = *(const float4*)(&Ws[ks][kk][colq*4]);
      float b0 = At[ks][kk][rp*2+0];
      float b1 = At[ks][kk][rp*2+1];
      a00 += b0*w.x; a01 += b0*w.y; a02 += b0*w.z; a03 += b0*w.w;
      a10 += b1*w.x; a11 += b1*w.y; a12 += b1*w.z; a13 += b1*w.w;
    }
    __builtin_amdgcn_wave_barrier();
  }

  if (ks > 0){
    float* part = &Ws[ks][0][0];
    *(float4*)(part + (rp*2+0)*64 + colq*4) = make_float4(a00,a01,a02,a03);
    *(float4*)(part + (rp*2+1)*64 + colq*4) = make_float4(a10,a11,a12,a13);
  }
  __syncthreads();
  if (ks == 0){
    float4 bv = *(const float4*)(bias + col0 + colq*4);
    float accr[2][4] = {{a00,a01,a02,a03},{a10,a11,a12,a13}};
#pragma unroll
    for (int r=0;r<2;r++){
      int off = (rp*2+r)*64 + colq*4;
      float sx = accr[r][0], sy = accr[r][1], sz = accr[r][2], sw = accr[r][3];
#pragma unroll
      for (int pw=1; pw<8; pw++){
        float4 pp = *(const float4*)(&Ws[pw][0][0] + off);
        sx += pp.x; sy += pp.y; sz += pp.z; sw += pp.w;
      }
      float4 o;
      o.x = lrelu(sx + bv.x);
      o.y = lrelu(sy + bv.y);
      o.z = lrelu(sz + bv.z);
      o.w = lrelu(sw + bv.w);
      *(float4*)(out + (size_t)(row0 + rp*2 + r)*C2 + col0 + colq*4) = o;
    }
  }
}

// ------------------------------------------------------------- final layer --
__global__ __launch_bounds__(64) void final_kernel(const float* __restrict__ g,
                                                   const float* __restrict__ Wo,
                                                   const float* __restrict__ bo,
                                                   float* __restrict__ out){
  int i = blockIdx.x*64 + threadIdx.x;
  if (i >= NB*NL) return;
  int r = i / NL, c = i - r*NL;
  const float* gr = g + (size_t)r*C2;
  float acc = bo[c];
  for (int k=0;k<C2;k++) acc += gr[k]*Wo[k*NL + c];
  if (c < 2) acc = tanhf(acc);
  out[i] = acc;
}

// ------------------------------------------------------------------ launch --
extern "C" void kernel_launch(void* const* d_in, const int* in_sizes, int n_in,
                              void* d_out, int out_size, void* d_ws, size_t ws_size,
                              hipStream_t stream){
  const float* x   = (const float*)d_in[0];
  const float* Wc1 = (const float*)d_in[1];
  const float* bc1 = (const float*)d_in[2];
  const float* Wc2 = (const float*)d_in[3];
  const float* bc2 = (const float*)d_in[4];
  const float* Wc3 = (const float*)d_in[5];
  const float* bc3 = (const float*)d_in[6];
  const float* bng = (const float*)d_in[7];
  const float* bnb = (const float*)d_in[8];
  const float* W1  = (const float*)d_in[9];
  const float* b1  = (const float*)d_in[10];
  const float* W2  = (const float*)d_in[11];
  const float* b2  = (const float*)d_in[12];
  const float* W3  = (const float*)d_in[13];
  const float* b3  = (const float*)d_in[14];
  const float* W4  = (const float*)d_in[15];
  const float* b4  = (const float*)d_in[16];
  const float* W5  = (const float*)d_in[17];
  const float* b5  = (const float*)d_in[18];
  const float* Wo  = (const float*)d_in[19];
  const float* bo  = (const float*)d_in[20];

  char* ws = (char*)d_ws;
  size_t o = 0;
  int*            knn  = (int*)           (ws + o); o += (size_t)NN*KNN*4;
  float*          gf   = (float*)         (ws + o); o += (size_t)NB*C2*4;
  float*          gt   = (float*)         (ws + o); o += (size_t)NB*C2*4;
  unsigned short* Wpk2 = (unsigned short*)(ws + o); o += (size_t)3*CC*CC*2;
  unsigned short* Wpk3 = (unsigned short*)(ws + o); o += (size_t)3*CC*CC*2;
  float*          scb  = (float*)         (ws + o); o += (size_t)C2*4;
  float*          shb  = (float*)         (ws + o); o += (size_t)C2*4;

  knnpack_kernel<<<NB*64 + 384, 256, 0, stream>>>(x, knn, Wc2, Wc3, Wpk2, Wpk3);

  conv_all_kernel<<<NB, 1024, 0, stream>>>(x, knn, Wc1, bc1, Wpk2, bc2, Wpk3, bc3, gf);

  bnstats_kernel<<<12, 256, 0, stream>>>(gf, bng, bnb, scb, shb);

  dim3 mgrid(12, 32);
  mlp_gemm_kernel<<<mgrid, 512, 0, stream>>>(gf, W1, b1, scb, shb, 1, gt);
  mlp_gemm_kernel<<<mgrid, 512, 0, stream>>>(gt, W2, b2, nullptr, nullptr, 0, gf);
  mlp_gemm_kernel<<<mgrid, 512, 0, stream>>>(gf, W3, b3, nullptr, nullptr, 0, gt);
  mlp_gemm_kernel<<<mgrid, 512, 0, stream>>>(gt, W4, b4, nullptr, nullptr, 0, gf);
  mlp_gemm_kernel<<<mgrid, 512, 0, stream>>>(gf, W5, b5, nullptr, nullptr, 0, gt);

  final_kernel<<<12, 64, 0, stream>>>(gt, Wo, bo, (float*)d_out);
}

// Round 3
// 367.845 us; speedup vs baseline: 1.0431x; 1.0431x over previous
//
#include <hip/hip_runtime.h>
#include <cstdint>
#include <cmath>

#define NB 256      // graphs (B)
#define MM 256      // nodes per graph
#define NN (NB*MM)  // 65536 nodes
#define KNN 15
#define FIN 7
#define CC 128
#define CCP 152     // padded LDS row stride (shorts): 304B = 76 dwords == 12 (mod 32).
                    // Row stride must be ==0 mod 8 shorts (b128 align), so row starts
                    // are pinned to 4-dword bank residues; 152 is the best of that
                    // family for MFMA A-frag reads (R12-16: 136 gave 4-way, 3.02M).
#define C2 768
#define NL 3
#define FINF 3.4e38f

__device__ __forceinline__ float lrelu(float v){ return v > 0.f ? v : 0.01f*v; }

__device__ __forceinline__ unsigned short f2bf(float f){
  unsigned u = __float_as_uint(f);
  return (unsigned short)((u + 0x7FFFu + ((u >> 16) & 1u)) >> 16);
}
__device__ __forceinline__ float bf2f(unsigned short h){
  return __uint_as_float(((unsigned)h) << 16);
}

__device__ __forceinline__ int mbcnt64(unsigned long long m){
  return (int)__builtin_amdgcn_mbcnt_hi((unsigned)(m >> 32),
              __builtin_amdgcn_mbcnt_lo((unsigned)m, 0u));
}

typedef short bf16x8 __attribute__((ext_vector_type(8)));
typedef float f32x4  __attribute__((ext_vector_type(4)));
typedef float f32x2  __attribute__((ext_vector_type(2)));

// ------------------------------------------- kNN + packW (merged dispatch) --
// Radix-select (R9: 143 -> 58 us). Parked: issue/SALU-bound, micro-variants
// neutral (R8) or negative (R4, R15-split). packW (384 trivial blocks) rides
// along in the same grid to save one dispatch gap.
__global__ __launch_bounds__(256) void knnpack_kernel(
    const float* __restrict__ x, int* __restrict__ knn,
    const float* __restrict__ W2src, const float* __restrict__ W3src,
    unsigned short* __restrict__ W2dst, unsigned short* __restrict__ W3dst){
  __shared__ float4 pos[MM];
  __shared__ float  sq[MM];
  __shared__ unsigned skey[4][16];
  __shared__ int      sidx[4][16];

  if (blockIdx.x >= NB*64){
    // ---- packW path: pack W into MFMA B-frag order ----
    int idx = (blockIdx.x - NB*64)*256 + threadIdx.x;
    if (idx < 2*3*CC*CC){
      const float* Wsrc = (idx < 3*CC*CC) ? W2src : W3src;
      unsigned short* Wdst = (idx < 3*CC*CC) ? W2dst : W3dst;
      int e = (idx < 3*CC*CC) ? idx : idx - 3*CC*CC;
      int kg = e >> 7;
      int nn = e & 127;
      int ck = kg >> 5, q = (kg >> 3) & 3, j = kg & 7;
      Wdst[(((ck*4 + q)*CC) + nn)*8 + j] = f2bf(Wsrc[e]);
    }
    return;
  }

  const int g = blockIdx.x >> 6;
  const int t = threadIdx.x;
  const float* xr = x + (size_t)(g*MM + t)*FIN;
  float4 p = make_float4(xr[0], xr[1], xr[2], xr[3]);
  pos[t] = p;
  sq[t]  = p.x*p.x + p.y*p.y + p.z*p.z + p.w*p.w;
  __syncthreads();

  const int i    = (blockIdx.x & 63)*4 + (t >> 6);
  const int wv   = t >> 6;
  const int lane = t & 63;
  const float4 pi = pos[i];
  const float  sqi = sq[i];

  unsigned key[4];
#pragma unroll
  for (int qq=0;qq<4;qq++){
    int j = qq*64 + lane;
    float4 pj = pos[j];
    float dot = pi.x*pj.x + pi.y*pj.y + pi.z*pj.z + pi.w*pj.w;
    float d2  = sqi + sq[j] - 2.f*dot;
    unsigned u = __float_as_uint(d2);
    u = ((int)u < 0) ? ~u : (u ^ 0x80000000u);
    key[qq] = (j == i) ? 0xFFFFFFFFu : u;
  }

  unsigned prefix = 0u;
#pragma unroll
  for (int bit=31; bit>=0; --bit){
    unsigned trial = prefix | (1u << bit);
    int c = __popcll(__ballot(key[0] < trial))
          + __popcll(__ballot(key[1] < trial))
          + __popcll(__ballot(key[2] < trial))
          + __popcll(__ballot(key[3] < trial));
    if (c < KNN) prefix = trial;
  }
  const unsigned K = prefix;

  int c_lt = __popcll(__ballot(key[0] < K)) + __popcll(__ballot(key[1] < K))
           + __popcll(__ballot(key[2] < K)) + __popcll(__ballot(key[3] < K));
  int need = KNN - c_lt;
  bool w[4];
  int eqbase = 0;
#pragma unroll
  for (int qq=0;qq<4;qq++){
    unsigned long long em = __ballot(key[qq] == K);
    int gr = eqbase + mbcnt64(em);
    w[qq] = (key[qq] < K) || ((key[qq] == K) && (gr < need));
    eqbase += __popcll(em);
  }

  int base2 = 0;
#pragma unroll
  for (int qq=0;qq<4;qq++){
    unsigned long long wm = __ballot(w[qq]);
    int rk = mbcnt64(wm);
    if (w[qq]){ skey[wv][base2+rk] = key[qq]; sidx[wv][base2+rk] = qq*64 + lane; }
    base2 += __popcll(wm);
  }
  __builtin_amdgcn_wave_barrier();

  if (lane < KNN){
    unsigned mk = skey[wv][lane]; int mi = sidx[wv][lane];
    int r = 0;
#pragma unroll
    for (int m=0;m<KNN;m++){
      unsigned ok = skey[wv][m]; int oi = sidx[wv][m];
      r += (ok < mk || (ok == mk && oi < mi)) ? 1 : 0;
    }
    knn[(size_t)(g*MM + i)*KNN + r] = g*MM + mi;
  }
}

// --------------------------------------------------------- conv helpers -----
// one neighbor-row accumulate (bit-exact unpack order: lo then hi per dword)
__device__ __forceinline__ void agg_accum(const unsigned short* __restrict__ src,
                                          int off,
                                          f32x2& s0, f32x2& s1, f32x2& s2, f32x2& s3){
  uint4 r = *(const uint4*)(src + off);
  f32x2 v;
  v[0] = __uint_as_float(r.x << 16); v[1] = __uint_as_float(r.x & 0xFFFF0000u); s0 += v;
  v[0] = __uint_as_float(r.y << 16); v[1] = __uint_as_float(r.y & 0xFFFF0000u); s1 += v;
  v[0] = __uint_as_float(r.z << 16); v[1] = __uint_as_float(r.z & 0xFFFF0000u); s2 += v;
  v[0] = __uint_as_float(r.w << 16); v[1] = __uint_as_float(r.w & 0xFFFF0000u); s3 += v;
}

// one agg work-item: 15 gathers + 1/15 scale + bf16 pack + store (verbatim math)
__device__ __forceinline__ void agg_iter(const unsigned short* __restrict__ src,
                                         unsigned short* __restrict__ dst,
                                         const unsigned* __restrict__ opk8,
                                         int rowoff, int c8){
  f32x2 s0 = {0.f,0.f}, s1 = {0.f,0.f}, s2 = {0.f,0.f}, s3 = {0.f,0.f};
#pragma unroll
  for (int kk=0; kk<7; ++kk){
    unsigned pk = opk8[kk];
    agg_accum(src, (int)(pk & 0xFFFFu) + c8, s0, s1, s2, s3);
    agg_accum(src, (int)(pk >> 16)    + c8, s0, s1, s2, s3);
  }
  agg_accum(src, (int)(opk8[7] & 0xFFFFu) + c8, s0, s1, s2, s3);
  const float inv = 1.f/15.f;
  uint4 o;
  o.x = (unsigned)f2bf(s0[0]*inv) | ((unsigned)f2bf(s0[1]*inv) << 16);
  o.y = (unsigned)f2bf(s1[0]*inv) | ((unsigned)f2bf(s1[1]*inv) << 16);
  o.z = (unsigned)f2bf(s2[0]*inv) | ((unsigned)f2bf(s2[1]*inv) << 16);
  o.w = (unsigned)f2bf(s3[0]*inv) | ((unsigned)f2bf(s3[1]*inv) << 16);
  *(uint4*)(dst + rowoff + c8) = o;
}

// one MFMA K-chunk (order-preserving: identical to old mfma_seg inner body)
__device__ __forceinline__ void mfma_chunk(const unsigned short* __restrict__ A,
                                           const unsigned short* __restrict__ Wpk,
                                           int ck, int rows0, int cols0,
                                           int n, int q, f32x4 (&acc)[2][4]){
  const int kc = ck & 3;
  const unsigned short* ab = A + (rows0 + n)*CCP + kc*32 + q*8;
  bf16x8 af[2];
#pragma unroll
  for (int i=0;i<2;i++) af[i] = *(const bf16x8*)(ab + i*16*CCP);
  const unsigned short* wb = Wpk + ((size_t)(ck*4 + q)*CC + cols0 + n)*8;
  bf16x8 bfr[4];
#pragma unroll
  for (int t=0;t<4;t++) bfr[t] = *(const bf16x8*)(wb + t*16*8);
#pragma unroll
  for (int i=0;i<2;i++)
#pragma unroll
    for (int t=0;t<4;t++)
      acc[i][t] = __builtin_amdgcn_mfma_f32_16x16x32_bf16(af[i], bfr[t], acc[i][t], 0, 0, 0);
}

__device__ __forceinline__ void conv_epilogue(const float* __restrict__ bvec,
                                              f32x4 (&acc)[2][4],
                                              unsigned short* __restrict__ dst,
                                              int rows0, int cols0, int n, int q){
  float bv[4];
#pragma unroll
  for (int t=0;t<4;t++) bv[t] = bvec[cols0 + t*16 + n];
#pragma unroll
  for (int i=0;i<2;i++)
#pragma unroll
    for (int t=0;t<4;t++)
#pragma unroll
      for (int r=0;r<4;r++){
        int row = rows0 + i*16 + q*4 + r;
        int col = cols0 + t*16 + n;
        dst[row*CCP + col] = f2bf(lrelu(acc[i][t][r] + bv[t]));
      }
}

// all-wave pool: waves 0-7 sum, waves 8-15 max (same add/max order as before
// -> bit-exact; doubles thread utilization of the pool phase). NOTE: no
// trailing barrier -- callers rely on: next phase never reads pool's scratch,
// never writes pool's source buffer before the next full barrier.
__device__ __forceinline__ void pool_block(const unsigned short* __restrict__ buf,
                                           float* __restrict__ gf_base,
                                           float (*smean)[CC], float (*smax)[CC],
                                           int tid){
  const int c = tid & 127;
  const int grp = tid >> 7;             // 0..7, wave-uniform
  if (grp < 4){
    float s = 0.f;
    for (int m=grp*64; m<grp*64+64; ++m) s += bf2f(buf[m*CCP + c]);
    smean[grp][c] = s;
  } else {
    const int gg = grp - 4;
    float mx = -FINF;
    for (int m=gg*64; m<gg*64+64; ++m) mx = fmaxf(mx, bf2f(buf[m*CCP + c]));
    smax[gg][c] = mx;
  }
  __syncthreads();
  if (tid < 128){
    gf_base[c] = (smean[0][c] + smean[1][c] + smean[2][c] + smean[3][c]) * (1.f/MM);
  } else if (tid < 256){
    gf_base[CC + c] = fmaxf(fmaxf(smax[0][c], smax[1][c]),
                            fmaxf(smax[2][c], smax[3][c]));
  }
}

// ---------------- conv layers 1+2+3 fully fused (one block per graph) -------
// Layer 1 (feat agg7 x2 + conv1) runs inside this kernel: h never touches
// global. Layers 2/3: MFMA chunks interleaved 1:1 with agg iterations --
// phase A reads bufX for BOTH agg-src and MFMA A-frags and writes only bufY,
// so no intra-phase hazard; barriers and MFMA accumulation order unchanged
// -> bit-exact. Neighbor offsets preloaded once (u16-packed, 32 VGPRs),
// AFTER layer 1 (first use is layer 2; keeping them live across layer 1 was
// free pressure).
// LDS: 2 x 76.0 KB bufs + 4 KB pool scratch = 156.0 KB -> 1 block/CU,
// 4 waves/SIMD, LDS-bound. amdgpu_waves_per_eu(4,4) clamps the allocator's
// occupancy range to exactly that, unlocking the 512/4 = 128-VGPR budget.
// R1/R2 lesson: launch_bounds(1024, 4)'s 2nd arg was IGNORED by codegen
// (bit-identical binary, VGPR stuck at 64 for an unreachable 8-wave target,
// ~110-reg live set spilled: 187 MB phantom WRITE_SIZE, 135 us).
__global__ __launch_bounds__(1024)
__attribute__((amdgpu_waves_per_eu(4, 4)))
void conv_all_kernel(
    const float* __restrict__ x,
    const int* __restrict__ knn,
    const float* __restrict__ Wc1, const float* __restrict__ bc1,
    const unsigned short* __restrict__ Wpk2, const float* __restrict__ b2,
    const unsigned short* __restrict__ Wpk3, const float* __restrict__ b3,
    float* __restrict__ gf){
  __shared__ __align__(16) unsigned short bufh[MM*CCP];   // 77824 B
  __shared__ __align__(16) unsigned short bufa[MM*CCP];   // 77824 B
  __shared__ float smean[4][CC], smax[4][CC];
  const int g   = blockIdx.x;
  const int tid = threadIdx.x;
  const int* kn_graph = knn + (size_t)g*MM*KNN;

  // ================= layer 1 (feat in bufa's space) =================
  {
    float (*feat)[24] = (float (*)[24])bufa;    // 24576 B < bufa
    for (int e=tid; e<MM*FIN; e+=1024){
      int nn = e / FIN, f = e - nn*FIN;
      feat[nn][f] = x[(size_t)g*MM*FIN + e];
    }
    __syncthreads();
    const bool active = tid < MM;
    int loc[KNN];
    if (active){
      const int* kn = kn_graph + tid*KNN;
#pragma unroll
      for (int k=0;k<KNN;k++) loc[k] = kn[k] & (MM-1);
#pragma unroll
      for (int c=0;c<FIN;c++){
        float s = 0.f;
#pragma unroll
        for (int k=0;k<KNN;k++) s += feat[loc[k]][c];
        feat[tid][FIN + c] = s * (1.f/15.f);
      }
    }
    __syncthreads();
    if (active){
#pragma unroll
      for (int c=0;c<FIN;c++){
        float s = 0.f;
#pragma unroll
        for (int k=0;k<KNN;k++) s += feat[loc[k]][FIN + c];
        feat[tid][2*FIN + c] = s * (1.f/15.f);
      }
    }
    __syncthreads();
    // conv1: 1024 threads, 8 segs x 32 nodes; write h into bufh (CCP layout)
    {
      const int cc_ = tid & 127;
      const int seg = tid >> 7;
      float wcol[3*FIN];
#pragma unroll
      for (int t2=0;t2<3*FIN;t2++) wcol[t2] = Wc1[t2*CC + cc_];
      const float bc = bc1[cc_];
      for (int nn=seg*32; nn<seg*32+32; ++nn){
        float4 f0 = *(const float4*)(&feat[nn][0]);
        float4 f1 = *(const float4*)(&feat[nn][4]);
        float4 f2 = *(const float4*)(&feat[nn][8]);
        float4 f3 = *(const float4*)(&feat[nn][12]);
        float4 f4 = *(const float4*)(&feat[nn][16]);
        float4 f5 = *(const float4*)(&feat[nn][20]);
        float fv[21] = {f0.x,f0.y,f0.z,f0.w, f1.x,f1.y,f1.z,f1.w,
                        f2.x,f2.y,f2.z,f2.w, f3.x,f3.y,f3.z,f3.w,
                        f4.x,f4.y,f4.z,f4.w, f5.x};
        float a1 = bc;
#pragma unroll
        for (int t2=0;t2<3*FIN;t2++) a1 += fv[t2]*wcol[t2];
        bufh[nn*CCP + cc_] = f2bf(lrelu(a1));
      }
    }
    __syncthreads();
    pool_block(bufh, gf + (size_t)g*C2, smean, smax, tid);
    // no barrier: phase A2 reads bufh (read-read with pool partials) and
    // writes only bufa (feat now dead); pool finals touch only smean/smax.
  }

  // ---- preload agg neighbor offsets (loc*CCP, u16-packed; same lists feed
  // all 4 agg calls of layers 2 and 3) ----
  const int nbase = tid >> 4;
  const int c8    = (tid & 15) * 8;
  unsigned opk[4][8];
#pragma unroll
  for (int it=0; it<4; ++it){
    const int* kn = kn_graph + (it*64 + nbase)*KNN;
#pragma unroll
    for (int kk=0; kk<8; ++kk){
      unsigned lo = (unsigned)((kn[2*kk] & (MM-1)) * CCP);
      unsigned hi = (kk < 7) ? (unsigned)((kn[2*kk+1] & (MM-1)) * CCP) : 0u;
      opk[it][kk] = lo | (hi << 16);
    }
  }

  const int wv   = tid >> 6, lane = tid & 63;
  const int n    = lane & 15, q = lane >> 4;
  const int rows0 = (wv & 7)*32;
  const int cols0 = (wv >> 3)*64;

  f32x4 acc[2][4];

  // ================= layer 2 =================
#pragma unroll
  for (int i=0;i<2;i++)
#pragma unroll
    for (int t=0;t<4;t++) acc[i][t] = (f32x4){0.f,0.f,0.f,0.f};
  // phase A: mfma(bufh ck0-3) interleaved with a1_2 = agg(bufh) -> bufa
#pragma unroll
  for (int it=0; it<4; ++it){
    mfma_chunk(bufh, Wpk2, it, rows0, cols0, n, q, acc);
    agg_iter(bufh, bufa, opk[it], (it*64 + nbase)*CCP, c8);
  }
  __syncthreads();
  // phase B: mfma(bufa ck4-7) interleaved with a2_2 = agg(bufa) -> bufh
#pragma unroll
  for (int it=0; it<4; ++it){
    mfma_chunk(bufa, Wpk2, 4+it, rows0, cols0, n, q, acc);
    agg_iter(bufa, bufh, opk[it], (it*64 + nbase)*CCP, c8);
  }
  __syncthreads();
  // phase C: mfma(bufh ck8-11) + epilogue -> bufa (h3 stays in LDS)
#pragma unroll
  for (int cki=0; cki<4; ++cki)
    mfma_chunk(bufh, Wpk2, 8+cki, rows0, cols0, n, q, acc);
  conv_epilogue(b2, acc, bufa, rows0, cols0, n, q);
  __syncthreads();
  pool_block(bufa, gf + (size_t)g*C2 + 2*CC, smean, smax, tid);
  // no barrier: phase A3 reads bufa (read-read with pool) and writes bufh.

  // ================= layer 3 (h3 = bufa) =================
#pragma unroll
  for (int i=0;i<2;i++)
#pragma unroll
    for (int t=0;t<4;t++) acc[i][t] = (f32x4){0.f,0.f,0.f,0.f};
#pragma unroll
  for (int it=0; it<4; ++it){
    mfma_chunk(bufa, Wpk3, it, rows0, cols0, n, q, acc);
    agg_iter(bufa, bufh, opk[it], (it*64 + nbase)*CCP, c8);
  }
  __syncthreads();
#pragma unroll
  for (int it=0; it<4; ++it){
    mfma_chunk(bufh, Wpk3, 4+it, rows0, cols0, n, q, acc);
    agg_iter(bufh, bufa, opk[it], (it*64 + nbase)*CCP, c8);
  }
  __syncthreads();
#pragma unroll
  for (int cki=0; cki<4; ++cki)
    mfma_chunk(bufa, Wpk3, 8+cki, rows0, cols0, n, q, acc);
  conv_epilogue(b3, acc, bufh, rows0, cols0, n, q);
  __syncthreads();
  pool_block(bufh, gf + (size_t)g*C2 + 4*CC, smean, smax, tid);
}

// ------------------------------------------------------ batchnorm (stats) ---
__global__ __launch_bounds__(256) void bnstats_kernel(const float* __restrict__ g,
                                                      const float* __restrict__ gamma,
                                                      const float* __restrict__ beta,
                                                      float* __restrict__ scb,
                                                      float* __restrict__ shb){
  __shared__ float ssum[4][64], ssq[4][64];
  const int cl = threadIdx.x & 63, rg = threadIdx.x >> 6;
  const int c  = blockIdx.x*64 + cl;
  float s=0.f, q=0.f;
  for (int r=rg*64; r<rg*64+64; r++){
    float v = g[(size_t)r*C2 + c];
    s += v; q += v*v;
  }
  ssum[rg][cl]=s; ssq[rg][cl]=q;
  __syncthreads();
  if (rg == 0){
    s = ssum[0][cl]+ssum[1][cl]+ssum[2][cl]+ssum[3][cl];
    q = ssq [0][cl]+ssq [1][cl]+ssq [2][cl]+ssq [3][cl];
    float mu  = s * (1.f/NB);
    float var = q * (1.f/NB) - mu*mu;
    float sc  = rsqrtf(var + 1e-5f) * gamma[c];
    scb[c] = sc;
    shb[c] = beta[c] - mu*sc;
  }
}

// -------------------------------------------------- MLP (wave-K-split GEMM) -
__global__ __launch_bounds__(512) void mlp_gemm_kernel(
    const float* __restrict__ A, const float* __restrict__ W,
    const float* __restrict__ bias,
    const float* __restrict__ scb, const float* __restrict__ shb, int affine,
    float* __restrict__ out){
  __shared__ float Ws[8][32][64];   // 64 KB
  __shared__ float At[8][32][10];   // 10 KB
  const int tid  = threadIdx.x;
  const int ks   = tid >> 6, lane = tid & 63;
  const int colq = lane & 15, rp = lane >> 4;
  const int col0 = blockIdx.x * 64;
  const int row0 = blockIdx.y * 8;

  float a00=0.f,a01=0.f,a02=0.f,a03=0.f;
  float a10=0.f,a11=0.f,a12=0.f,a13=0.f;

  for (int kt=0; kt<3; kt++){
    const int kc0 = ks*96 + kt*32;
#pragma unroll
    for (int i=0;i<8;i++){
      int idx = i*256 + lane*4;
      int kr = idx >> 6, cc = idx & 63;
      *(float4*)(&Ws[ks][kr][cc]) =
          *(const float4*)(W + (size_t)(kc0+kr)*C2 + col0 + cc);
    }
    {
      int row = lane >> 3, kq = lane & 7;
      float4 a = *(const float4*)(A + (size_t)(row0+row)*C2 + kc0 + kq*4);
      if (affine){
        float4 s4 = *(const float4*)(scb + kc0 + kq*4);
        float4 h4 = *(const float4*)(shb + kc0 + kq*4);
        a.x = a.x*s4.x + h4.x; a.y = a.y*s4.y + h4.y;
        a.z = a.z*s4.z + h4.z; a.w = a.w*s4.w + h4.w;
      }
      At[ks][kq*4+0][row] = a.x;
      At[ks][kq*4+1][row] = a.y;
      At[ks][kq*4+2][row] = a.z;
      At[ks][kq*4+3][row] = a.w;
    }
    __builtin_amdgcn_wave_barrier();
#pragma unroll 8
    for (int kk=0;kk<32;kk++){
      float4 w = *(const float4*)(&Ws[ks][kk][colq*4]);
      float b0 = At[ks][kk][rp*2+0];
      float b1 = At[ks][kk][rp*2+1];
      a00 += b0*w.x; a01 += b0*w.y; a02 += b0*w.z; a03 += b0*w.w;
      a10 += b1*w.x; a11 += b1*w.y; a12 += b1*w.z; a13 += b1*w.w;
    }
    __builtin_amdgcn_wave_barrier();
  }

  if (ks > 0){
    float* part = &Ws[ks][0][0];
    *(float4*)(part + (rp*2+0)*64 + colq*4) = make_float4(a00,a01,a02,a03);
    *(float4*)(part + (rp*2+1)*64 + colq*4) = make_float4(a10,a11,a12,a13);
  }
  __syncthreads();
  if (ks == 0){
    float4 bv = *(const float4*)(bias + col0 + colq*4);
    float accr[2][4] = {{a00,a01,a02,a03},{a10,a11,a12,a13}};
#pragma unroll
    for (int r=0;r<2;r++){
      int off = (rp*2+r)*64 + colq*4;
      float sx = accr[r][0], sy = accr[r][1], sz = accr[r][2], sw = accr[r][3];
#pragma unroll
      for (int pw=1; pw<8; pw++){
        float4 pp = *(const float4*)(&Ws[pw][0][0] + off);
        sx += pp.x; sy += pp.y; sz += pp.z; sw += pp.w;
      }
      float4 o;
      o.x = lrelu(sx + bv.x);
      o.y = lrelu(sy + bv.y);
      o.z = lrelu(sz + bv.z);
      o.w = lrelu(sw + bv.w);
      *(float4*)(out + (size_t)(row0 + rp*2 + r)*C2 + col0 + colq*4) = o;
    }
  }
}

// ------------------------------------------------------------- final layer --
__global__ __launch_bounds__(64) void final_kernel(const float* __restrict__ g,
                                                   const float* __restrict__ Wo,
                                                   const float* __restrict__ bo,
                                                   float* __restrict__ out){
  int i = blockIdx.x*64 + threadIdx.x;
  if (i >= NB*NL) return;
  int r = i / NL, c = i - r*NL;
  const float* gr = g + (size_t)r*C2;
  float acc = bo[c];
  for (int k=0;k<C2;k++) acc += gr[k]*Wo[k*NL + c];
  if (c < 2) acc = tanhf(acc);
  out[i] = acc;
}

// ------------------------------------------------------------------ launch --
extern "C" void kernel_launch(void* const* d_in, const int* in_sizes, int n_in,
                              void* d_out, int out_size, void* d_ws, size_t ws_size,
                              hipStream_t stream){
  const float* x   = (const float*)d_in[0];
  const float* Wc1 = (const float*)d_in[1];
  const float* bc1 = (const float*)d_in[2];
  const float* Wc2 = (const float*)d_in[3];
  const float* bc2 = (const float*)d_in[4];
  const float* Wc3 = (const float*)d_in[5];
  const float* bc3 = (const float*)d_in[6];
  const float* bng = (const float*)d_in[7];
  const float* bnb = (const float*)d_in[8];
  const float* W1  = (const float*)d_in[9];
  const float* b1  = (const float*)d_in[10];
  const float* W2  = (const float*)d_in[11];
  const float* b2  = (const float*)d_in[12];
  const float* W3  = (const float*)d_in[13];
  const float* b3  = (const float*)d_in[14];
  const float* W4  = (const float*)d_in[15];
  const float* b4  = (const float*)d_in[16];
  const float* W5  = (const float*)d_in[17];
  const float* b5  = (const float*)d_in[18];
  const float* Wo  = (const float*)d_in[19];
  const float* bo  = (const float*)d_in[20];

  char* ws = (char*)d_ws;
  size_t o = 0;
  int*            knn  = (int*)           (ws + o); o += (size_t)NN*KNN*4;
  float*          gf   = (float*)         (ws + o); o += (size_t)NB*C2*4;
  float*          gt   = (float*)         (ws + o); o += (size_t)NB*C2*4;
  unsigned short* Wpk2 = (unsigned short*)(ws + o); o += (size_t)3*CC*CC*2;
  unsigned short* Wpk3 = (unsigned short*)(ws + o); o += (size_t)3*CC*CC*2;
  float*          scb  = (float*)         (ws + o); o += (size_t)C2*4;
  float*          shb  = (float*)         (ws + o); o += (size_t)C2*4;

  knnpack_kernel<<<NB*64 + 384, 256, 0, stream>>>(x, knn, Wc2, Wc3, Wpk2, Wpk3);

  conv_all_kernel<<<NB, 1024, 0, stream>>>(x, knn, Wc1, bc1, Wpk2, bc2, Wpk3, bc3, gf);

  bnstats_kernel<<<12, 256, 0, stream>>>(gf, bng, bnb, scb, shb);

  dim3 mgrid(12, 32);
  mlp_gemm_kernel<<<mgrid, 512, 0, stream>>>(gf, W1, b1, scb, shb, 1, gt);
  mlp_gemm_kernel<<<mgrid, 512, 0, stream>>>(gt, W2, b2, nullptr, nullptr, 0, gf);
  mlp_gemm_kernel<<<mgrid, 512, 0, stream>>>(gf, W3, b3, nullptr, nullptr, 0, gt);
  mlp_gemm_kernel<<<mgrid, 512, 0, stream>>>(gt, W4, b4, nullptr, nullptr, 0, gf);
  mlp_gemm_kernel<<<mgrid, 512, 0, stream>>>(gf, W5, b5, nullptr, nullptr, 0, gt);

  final_kernel<<<12, 64, 0, stream>>>(gt, Wo, bo, (float*)d_out);
}

// Round 4
// 323.887 us; speedup vs baseline: 1.1847x; 1.1357x over previous
//
#include <hip/hip_runtime.h>
#include <cstdint>
#include <cmath>

#define NB 256      // graphs (B)
#define MM 256      // nodes per graph
#define NN (NB*MM)  // 65536 nodes
#define KNN 15
#define FIN 7
#define CC 128
#define CCP 152     // padded LDS row stride (shorts): 304B = 76 dwords == 12 (mod 32).
                    // Row stride must be ==0 mod 8 shorts (b128 align), so row starts
                    // are pinned to 4-dword bank residues; 152 is the best of that
                    // family for MFMA A-frag reads (R12-16: 136 gave 4-way, 3.02M).
#define C2 768
#define NL 3
#define FINF 3.4e38f

__device__ __forceinline__ float lrelu(float v){ return v > 0.f ? v : 0.01f*v; }

__device__ __forceinline__ unsigned short f2bf(float f){
  unsigned u = __float_as_uint(f);
  return (unsigned short)((u + 0x7FFFu + ((u >> 16) & 1u)) >> 16);
}
__device__ __forceinline__ float bf2f(unsigned short h){
  return __uint_as_float(((unsigned)h) << 16);
}

__device__ __forceinline__ int mbcnt64(unsigned long long m){
  return (int)__builtin_amdgcn_mbcnt_hi((unsigned)(m >> 32),
              __builtin_amdgcn_mbcnt_lo((unsigned)m, 0u));
}

typedef short bf16x8 __attribute__((ext_vector_type(8)));
typedef float f32x4  __attribute__((ext_vector_type(4)));

// ------------------------------------------- kNN + packW (merged dispatch) --
// Radix-select (R9: 143 -> 58 us). Parked: issue/SALU-bound, micro-variants
// neutral (R8) or negative (R4, R15-split). packW (384 trivial blocks) rides
// along in the same grid to save one dispatch gap.
__global__ __launch_bounds__(256) void knnpack_kernel(
    const float* __restrict__ x, int* __restrict__ knn,
    const float* __restrict__ W2src, const float* __restrict__ W3src,
    unsigned short* __restrict__ W2dst, unsigned short* __restrict__ W3dst){
  __shared__ float4 pos[MM];
  __shared__ float  sq[MM];
  __shared__ unsigned skey[4][16];
  __shared__ int      sidx[4][16];

  if (blockIdx.x >= NB*64){
    // ---- packW path: pack W into MFMA B-frag order ----
    int idx = (blockIdx.x - NB*64)*256 + threadIdx.x;
    if (idx < 2*3*CC*CC){
      const float* Wsrc = (idx < 3*CC*CC) ? W2src : W3src;
      unsigned short* Wdst = (idx < 3*CC*CC) ? W2dst : W3dst;
      int e = (idx < 3*CC*CC) ? idx : idx - 3*CC*CC;
      int kg = e >> 7;
      int nn = e & 127;
      int ck = kg >> 5, q = (kg >> 3) & 3, j = kg & 7;
      Wdst[(((ck*4 + q)*CC) + nn)*8 + j] = f2bf(Wsrc[e]);
    }
    return;
  }

  const int g = blockIdx.x >> 6;
  const int t = threadIdx.x;
  const float* xr = x + (size_t)(g*MM + t)*FIN;
  float4 p = make_float4(xr[0], xr[1], xr[2], xr[3]);
  pos[t] = p;
  sq[t]  = p.x*p.x + p.y*p.y + p.z*p.z + p.w*p.w;
  __syncthreads();

  const int i    = (blockIdx.x & 63)*4 + (t >> 6);
  const int wv   = t >> 6;
  const int lane = t & 63;
  const float4 pi = pos[i];
  const float  sqi = sq[i];

  unsigned key[4];
#pragma unroll
  for (int qq=0;qq<4;qq++){
    int j = qq*64 + lane;
    float4 pj = pos[j];
    float dot = pi.x*pj.x + pi.y*pj.y + pi.z*pj.z + pi.w*pj.w;
    float d2  = sqi + sq[j] - 2.f*dot;
    unsigned u = __float_as_uint(d2);
    u = ((int)u < 0) ? ~u : (u ^ 0x80000000u);
    key[qq] = (j == i) ? 0xFFFFFFFFu : u;
  }

  unsigned prefix = 0u;
#pragma unroll
  for (int bit=31; bit>=0; --bit){
    unsigned trial = prefix | (1u << bit);
    int c = __popcll(__ballot(key[0] < trial))
          + __popcll(__ballot(key[1] < trial))
          + __popcll(__ballot(key[2] < trial))
          + __popcll(__ballot(key[3] < trial));
    if (c < KNN) prefix = trial;
  }
  const unsigned K = prefix;

  int c_lt = __popcll(__ballot(key[0] < K)) + __popcll(__ballot(key[1] < K))
           + __popcll(__ballot(key[2] < K)) + __popcll(__ballot(key[3] < K));
  int need = KNN - c_lt;
  bool w[4];
  int eqbase = 0;
#pragma unroll
  for (int qq=0;qq<4;qq++){
    unsigned long long em = __ballot(key[qq] == K);
    int gr = eqbase + mbcnt64(em);
    w[qq] = (key[qq] < K) || ((key[qq] == K) && (gr < need));
    eqbase += __popcll(em);
  }

  int base2 = 0;
#pragma unroll
  for (int qq=0;qq<4;qq++){
    unsigned long long wm = __ballot(w[qq]);
    int rk = mbcnt64(wm);
    if (w[qq]){ skey[wv][base2+rk] = key[qq]; sidx[wv][base2+rk] = qq*64 + lane; }
    base2 += __popcll(wm);
  }
  __builtin_amdgcn_wave_barrier();

  if (lane < KNN){
    unsigned mk = skey[wv][lane]; int mi = sidx[wv][lane];
    int r = 0;
#pragma unroll
    for (int m=0;m<KNN;m++){
      unsigned ok = skey[wv][m]; int oi = sidx[wv][m];
      r += (ok < mk || (ok == mk && oi < mi)) ? 1 : 0;
    }
    knn[(size_t)(g*MM + i)*KNN + r] = g*MM + mi;
  }
}

// ---------------------- exact agg128 arithmetic, LDS->LDS (1024 threads) ----
// R0-verbatim (reads kn from global each call): keeps the transient register
// footprint small enough that acc[2][4] stays in AGPRs (R0: VGPR 56, zero
// spill). R1-R3 lesson: the opk register cache + 1:1 MFMA interleave pushed
// the live set to ~110 regs, the allocator is hard-pinned at 64 VGPRs on
// this toolchain (launch_bounds(,4) AND amdgpu_waves_per_eu(4,4) both
// ignored), and everything spilled: 174-187 MB phantom WRITE_SIZE, 121-135us.
__device__ __forceinline__ void agg_lds(const unsigned short* __restrict__ src,
                                        unsigned short* __restrict__ dst,
                                        const int* __restrict__ kn_graph,
                                        int tid){
  for (int it=0; it<4; ++it){
    int idx = it*1024 + tid;
    int nn  = idx >> 4;
    int c8  = (idx & 15) * 8;
    const int* kn = kn_graph + nn*KNN;
    float s[8];
#pragma unroll
    for (int e=0;e<8;e++) s[e]=0.f;
#pragma unroll
    for (int k=0;k<KNN;k++){
      int loc = kn[k] & (MM-1);
      uint4 r = *(const uint4*)(src + loc*CCP + c8);
      s[0] += __uint_as_float(r.x << 16); s[1] += __uint_as_float(r.x & 0xFFFF0000u);
      s[2] += __uint_as_float(r.y << 16); s[3] += __uint_as_float(r.y & 0xFFFF0000u);
      s[4] += __uint_as_float(r.z << 16); s[5] += __uint_as_float(r.z & 0xFFFF0000u);
      s[6] += __uint_as_float(r.w << 16); s[7] += __uint_as_float(r.w & 0xFFFF0000u);
    }
    const float inv = 1.f/15.f;
    uint4 o;
    o.x = (unsigned)f2bf(s[0]*inv) | ((unsigned)f2bf(s[1]*inv) << 16);
    o.y = (unsigned)f2bf(s[2]*inv) | ((unsigned)f2bf(s[3]*inv) << 16);
    o.z = (unsigned)f2bf(s[4]*inv) | ((unsigned)f2bf(s[5]*inv) << 16);
    o.w = (unsigned)f2bf(s[6]*inv) | ((unsigned)f2bf(s[7]*inv) << 16);
    *(uint4*)(dst + nn*CCP + c8) = o;
  }
}

// 4 consecutive MFMA K-chunks from one A buffer (order-preserving helper)
__device__ __forceinline__ void mfma_seg(const unsigned short* __restrict__ A,
                                         const unsigned short* __restrict__ Wpk,
                                         int ck0, int rows0, int cols0,
                                         int n, int q, f32x4 (&acc)[2][4]){
#pragma unroll
  for (int cki=0; cki<4; cki++){
    const int ck = ck0 + cki;
    const int kc = ck & 3;
    const unsigned short* ab = A + (rows0 + n)*CCP + kc*32 + q*8;
    bf16x8 af[2];
#pragma unroll
    for (int i=0;i<2;i++) af[i] = *(const bf16x8*)(ab + i*16*CCP);
    const unsigned short* wb = Wpk + ((size_t)(ck*4 + q)*CC + cols0 + n)*8;
    bf16x8 bfr[4];
#pragma unroll
    for (int t=0;t<4;t++) bfr[t] = *(const bf16x8*)(wb + t*16*8);
#pragma unroll
    for (int i=0;i<2;i++)
#pragma unroll
      for (int t=0;t<4;t++)
        acc[i][t] = __builtin_amdgcn_mfma_f32_16x16x32_bf16(af[i], bfr[t], acc[i][t], 0, 0, 0);
  }
}

__device__ __forceinline__ void conv_epilogue(const float* __restrict__ bvec,
                                              f32x4 (&acc)[2][4],
                                              unsigned short* __restrict__ dst,
                                              int rows0, int cols0, int n, int q){
  float bv[4];
#pragma unroll
  for (int t=0;t<4;t++) bv[t] = bvec[cols0 + t*16 + n];
#pragma unroll
  for (int i=0;i<2;i++)
#pragma unroll
    for (int t=0;t<4;t++)
#pragma unroll
      for (int r=0;r<4;r++){
        int row = rows0 + i*16 + q*4 + r;
        int col = cols0 + t*16 + n;
        dst[row*CCP + col] = f2bf(lrelu(acc[i][t][r] + bv[t]));
      }
}

// all-wave pool: waves 0-7 sum, waves 8-15 max (same add/max order as the
// original serial version -> bit-exact; doubles pool-phase utilization).
// NOTE: no trailing barrier -- callers rely on: the next phase never reads
// pool's scratch and never writes pool's source buffer before the next
// full barrier.
__device__ __forceinline__ void pool_block(const unsigned short* __restrict__ buf,
                                           float* __restrict__ gf_base,
                                           float (*smean)[CC], float (*smax)[CC],
                                           int tid){
  const int c = tid & 127;
  const int grp = tid >> 7;             // 0..7, wave-uniform
  if (grp < 4){
    float s = 0.f;
    for (int m=grp*64; m<grp*64+64; ++m) s += bf2f(buf[m*CCP + c]);
    smean[grp][c] = s;
  } else {
    const int gg = grp - 4;
    float mx = -FINF;
    for (int m=gg*64; m<gg*64+64; ++m) mx = fmaxf(mx, bf2f(buf[m*CCP + c]));
    smax[gg][c] = mx;
  }
  __syncthreads();
  if (tid < 128){
    gf_base[c] = (smean[0][c] + smean[1][c] + smean[2][c] + smean[3][c]) * (1.f/MM);
  } else if (tid < 256){
    gf_base[CC + c] = fmaxf(fmaxf(smax[0][c], smax[1][c]),
                            fmaxf(smax[2][c], smax[3][c]));
  }
}

// ---------------- conv layers 1+2+3 fully fused (one block per graph) -------
// Layer 1 (feat agg7 x2 + conv1) runs inside this kernel: h never touches
// global (removes a dispatch + 32 MB round-trip + conv23's staging phase).
// Layers 2/3 use R0's PHASE-SEPARATED schedule (agg | barrier | MFMA), the
// structure proven to compile at 56 VGPR with AGPR accumulators and zero
// scratch. The R1-R3 interleaved variant is refuted on this toolchain (see
// agg_lds comment). LDS: 2 x 76 KB bufs + 4 KB pool scratch = 156 KB ->
// 1 block/CU, 4 waves/SIMD.
__global__ __launch_bounds__(1024) void conv_all_kernel(
    const float* __restrict__ x,
    const int* __restrict__ knn,
    const float* __restrict__ Wc1, const float* __restrict__ bc1,
    const unsigned short* __restrict__ Wpk2, const float* __restrict__ b2,
    const unsigned short* __restrict__ Wpk3, const float* __restrict__ b3,
    float* __restrict__ gf){
  __shared__ __align__(16) unsigned short bufh[MM*CCP];   // 77824 B
  __shared__ __align__(16) unsigned short bufa[MM*CCP];   // 77824 B
  __shared__ float smean[4][CC], smax[4][CC];
  const int g   = blockIdx.x;
  const int tid = threadIdx.x;
  const int* kn_graph = knn + (size_t)g*MM*KNN;

  // ================= layer 1 (feat in bufa's space) =================
  {
    float (*feat)[24] = (float (*)[24])bufa;    // 24576 B < bufa
    for (int e=tid; e<MM*FIN; e+=1024){
      int nn = e / FIN, f = e - nn*FIN;
      feat[nn][f] = x[(size_t)g*MM*FIN + e];
    }
    __syncthreads();
    const bool active = tid < MM;
    int loc[KNN];
    if (active){
      const int* kn = kn_graph + tid*KNN;
#pragma unroll
      for (int k=0;k<KNN;k++) loc[k] = kn[k] & (MM-1);
#pragma unroll
      for (int c=0;c<FIN;c++){
        float s = 0.f;
#pragma unroll
        for (int k=0;k<KNN;k++) s += feat[loc[k]][c];
        feat[tid][FIN + c] = s * (1.f/15.f);
      }
    }
    __syncthreads();
    if (active){
#pragma unroll
      for (int c=0;c<FIN;c++){
        float s = 0.f;
#pragma unroll
        for (int k=0;k<KNN;k++) s += feat[loc[k]][FIN + c];
        feat[tid][2*FIN + c] = s * (1.f/15.f);
      }
    }
    __syncthreads();
    // conv1: 1024 threads, 8 segs x 32 nodes; write h into bufh (CCP layout)
    {
      const int cc_ = tid & 127;
      const int seg = tid >> 7;
      float wcol[3*FIN];
#pragma unroll
      for (int t2=0;t2<3*FIN;t2++) wcol[t2] = Wc1[t2*CC + cc_];
      const float bc = bc1[cc_];
      for (int nn=seg*32; nn<seg*32+32; ++nn){
        float4 f0 = *(const float4*)(&feat[nn][0]);
        float4 f1 = *(const float4*)(&feat[nn][4]);
        float4 f2 = *(const float4*)(&feat[nn][8]);
        float4 f3 = *(const float4*)(&feat[nn][12]);
        float4 f4 = *(const float4*)(&feat[nn][16]);
        float4 f5 = *(const float4*)(&feat[nn][20]);
        float fv[21] = {f0.x,f0.y,f0.z,f0.w, f1.x,f1.y,f1.z,f1.w,
                        f2.x,f2.y,f2.z,f2.w, f3.x,f3.y,f3.z,f3.w,
                        f4.x,f4.y,f4.z,f4.w, f5.x};
        float a1 = bc;
#pragma unroll
        for (int t2=0;t2<3*FIN;t2++) a1 += fv[t2]*wcol[t2];
        bufh[nn*CCP + cc_] = f2bf(lrelu(a1));
      }
    }
    __syncthreads();
    pool_block(bufh, gf + (size_t)g*C2, smean, smax, tid);
    // no barrier: the next agg reads bufh (read-read with pool partials) and
    // writes only bufa (feat now dead); pool finals touch only smean/smax.
  }

  const int wv   = tid >> 6, lane = tid & 63;
  const int n    = lane & 15, q = lane >> 4;
  const int rows0 = (wv & 7)*32;
  const int cols0 = (wv >> 3)*64;

  f32x4 acc[2][4];

  // ================= layer 2 =================
  agg_lds(bufh, bufa, kn_graph, tid);   // a1_2 = agg(h)
  __syncthreads();
#pragma unroll
  for (int i=0;i<2;i++)
#pragma unroll
    for (int t=0;t<4;t++) acc[i][t] = (f32x4){0.f,0.f,0.f,0.f};
  mfma_seg(bufh, Wpk2, 0, rows0, cols0, n, q, acc);   // ck0-3 (h)
  mfma_seg(bufa, Wpk2, 4, rows0, cols0, n, q, acc);   // ck4-7 (a1)
  __syncthreads();
  agg_lds(bufa, bufh, kn_graph, tid);   // a2_2 = agg(a1), overwrites h
  __syncthreads();
  mfma_seg(bufh, Wpk2, 8, rows0, cols0, n, q, acc);   // ck8-11 (a2)
  conv_epilogue(b2, acc, bufa, rows0, cols0, n, q);   // h3 -> bufa (stays in LDS)
  __syncthreads();
  pool_block(bufa, gf + (size_t)g*C2 + 2*CC, smean, smax, tid);
  // no barrier: next agg reads bufa (read-read with pool) and writes bufh.

  // ================= layer 3 (h3 = bufa) =================
  agg_lds(bufa, bufh, kn_graph, tid);   // a1_3 = agg(h3)
  __syncthreads();
#pragma unroll
  for (int i=0;i<2;i++)
#pragma unroll
    for (int t=0;t<4;t++) acc[i][t] = (f32x4){0.f,0.f,0.f,0.f};
  mfma_seg(bufa, Wpk3, 0, rows0, cols0, n, q, acc);   // ck0-3 (h3)
  mfma_seg(bufh, Wpk3, 4, rows0, cols0, n, q, acc);   // ck4-7 (a1_3)
  __syncthreads();
  agg_lds(bufh, bufa, kn_graph, tid);   // a2_3 = agg(a1_3), overwrites h3
  __syncthreads();
  mfma_seg(bufa, Wpk3, 8, rows0, cols0, n, q, acc);   // ck8-11 (a2_3)
  conv_epilogue(b3, acc, bufh, rows0, cols0, n, q);   // only the pool reads it
  __syncthreads();
  pool_block(bufh, gf + (size_t)g*C2 + 4*CC, smean, smax, tid);
}

// ------------------------------------------------------ batchnorm (stats) ---
__global__ __launch_bounds__(256) void bnstats_kernel(const float* __restrict__ g,
                                                      const float* __restrict__ gamma,
                                                      const float* __restrict__ beta,
                                                      float* __restrict__ scb,
                                                      float* __restrict__ shb){
  __shared__ float ssum[4][64], ssq[4][64];
  const int cl = threadIdx.x & 63, rg = threadIdx.x >> 6;
  const int c  = blockIdx.x*64 + cl;
  float s=0.f, q=0.f;
  for (int r=rg*64; r<rg*64+64; r++){
    float v = g[(size_t)r*C2 + c];
    s += v; q += v*v;
  }
  ssum[rg][cl]=s; ssq[rg][cl]=q;
  __syncthreads();
  if (rg == 0){
    s = ssum[0][cl]+ssum[1][cl]+ssum[2][cl]+ssum[3][cl];
    q = ssq [0][cl]+ssq [1][cl]+ssq [2][cl]+ssq [3][cl];
    float mu  = s * (1.f/NB);
    float var = q * (1.f/NB) - mu*mu;
    float sc  = rsqrtf(var + 1e-5f) * gamma[c];
    scb[c] = sc;
    shb[c] = beta[c] - mu*sc;
  }
}

// -------------------------------------------------- MLP (wave-K-split GEMM) -
__global__ __launch_bounds__(512) void mlp_gemm_kernel(
    const float* __restrict__ A, const float* __restrict__ W,
    const float* __restrict__ bias,
    const float* __restrict__ scb, const float* __restrict__ shb, int affine,
    float* __restrict__ out){
  __shared__ float Ws[8][32][64];   // 64 KB
  __shared__ float At[8][32][10];   // 10 KB
  const int tid  = threadIdx.x;
  const int ks   = tid >> 6, lane = tid & 63;
  const int colq = lane & 15, rp = lane >> 4;
  const int col0 = blockIdx.x * 64;
  const int row0 = blockIdx.y * 8;

  float a00=0.f,a01=0.f,a02=0.f,a03=0.f;
  float a10=0.f,a11=0.f,a12=0.f,a13=0.f;

  for (int kt=0; kt<3; kt++){
    const int kc0 = ks*96 + kt*32;
#pragma unroll
    for (int i=0;i<8;i++){
      int idx = i*256 + lane*4;
      int kr = idx >> 6, cc = idx & 63;
      *(float4*)(&Ws[ks][kr][cc]) =
          *(const float4*)(W + (size_t)(kc0+kr)*C2 + col0 + cc);
    }
    {
      int row = lane >> 3, kq = lane & 7;
      float4 a = *(const float4*)(A + (size_t)(row0+row)*C2 + kc0 + kq*4);
      if (affine){
        float4 s4 = *(const float4*)(scb + kc0 + kq*4);
        float4 h4 = *(const float4*)(shb + kc0 + kq*4);
        a.x = a.x*s4.x + h4.x; a.y = a.y*s4.y + h4.y;
        a.z = a.z*s4.z + h4.z; a.w = a.w*s4.w + h4.w;
      }
      At[ks][kq*4+0][row] = a.x;
      At[ks][kq*4+1][row] = a.y;
      At[ks][kq*4+2][row] = a.z;
      At[ks][kq*4+3][row] = a.w;
    }
    __builtin_amdgcn_wave_barrier();
#pragma unroll 8
    for (int kk=0;kk<32;kk++){
      float4 w = *(const float4*)(&Ws[ks][kk][colq*4]);
      float b0 = At[ks][kk][rp*2+0];
      float b1 = At[ks][kk][rp*2+1];
      a00 += b0*w.x; a01 += b0*w.y; a02 += b0*w.z; a03 += b0*w.w;
      a10 += b1*w.x; a11 += b1*w.y; a12 += b1*w.z; a13 += b1*w.w;
    }
    __builtin_amdgcn_wave_barrier();
  }

  if (ks > 0){
    float* part = &Ws[ks][0][0];
    *(float4*)(part + (rp*2+0)*64 + colq*4) = make_float4(a00,a01,a02,a03);
    *(float4*)(part + (rp*2+1)*64 + colq*4) = make_float4(a10,a11,a12,a13);
  }
  __syncthreads();
  if (ks == 0){
    float4 bv = *(const float4*)(bias + col0 + colq*4);
    float accr[2][4] = {{a00,a01,a02,a03},{a10,a11,a12,a13}};
#pragma unroll
    for (int r=0;r<2;r++){
      int off = (rp*2+r)*64 + colq*4;
      float sx = accr[r][0], sy = accr[r][1], sz = accr[r][2], sw = accr[r][3];
#pragma unroll
      for (int pw=1; pw<8; pw++){
        float4 pp = *(const float4*)(&Ws[pw][0][0] + off);
        sx += pp.x; sy += pp.y; sz += pp.z; sw += pp.w;
      }
      float4 o;
      o.x = lrelu(sx + bv.x);
      o.y = lrelu(sy + bv.y);
      o.z = lrelu(sz + bv.z);
      o.w = lrelu(sw + bv.w);
      *(float4*)(out + (size_t)(row0 + rp*2 + r)*C2 + col0 + colq*4) = o;
    }
  }
}

// ------------------------------------------------------------- final layer --
__global__ __launch_bounds__(64) void final_kernel(const float* __restrict__ g,
                                                   const float* __restrict__ Wo,
                                                   const float* __restrict__ bo,
                                                   float* __restrict__ out){
  int i = blockIdx.x*64 + threadIdx.x;
  if (i >= NB*NL) return;
  int r = i / NL, c = i - r*NL;
  const float* gr = g + (size_t)r*C2;
  float acc = bo[c];
  for (int k=0;k<C2;k++) acc += gr[k]*Wo[k*NL + c];
  if (c < 2) acc = tanhf(acc);
  out[i] = acc;
}

// ------------------------------------------------------------------ launch --
extern "C" void kernel_launch(void* const* d_in, const int* in_sizes, int n_in,
                              void* d_out, int out_size, void* d_ws, size_t ws_size,
                              hipStream_t stream){
  const float* x   = (const float*)d_in[0];
  const float* Wc1 = (const float*)d_in[1];
  const float* bc1 = (const float*)d_in[2];
  const float* Wc2 = (const float*)d_in[3];
  const float* bc2 = (const float*)d_in[4];
  const float* Wc3 = (const float*)d_in[5];
  const float* bc3 = (const float*)d_in[6];
  const float* bng = (const float*)d_in[7];
  const float* bnb = (const float*)d_in[8];
  const float* W1  = (const float*)d_in[9];
  const float* b1  = (const float*)d_in[10];
  const float* W2  = (const float*)d_in[11];
  const float* b2  = (const float*)d_in[12];
  const float* W3  = (const float*)d_in[13];
  const float* b3  = (const float*)d_in[14];
  const float* W4  = (const float*)d_in[15];
  const float* b4  = (const float*)d_in[16];
  const float* W5  = (const float*)d_in[17];
  const float* b5  = (const float*)d_in[18];
  const float* Wo  = (const float*)d_in[19];
  const float* bo  = (const float*)d_in[20];

  char* ws = (char*)d_ws;
  size_t o = 0;
  int*            knn  = (int*)           (ws + o); o += (size_t)NN*KNN*4;
  float*          gf   = (float*)         (ws + o); o += (size_t)NB*C2*4;
  float*          gt   = (float*)         (ws + o); o += (size_t)NB*C2*4;
  unsigned short* Wpk2 = (unsigned short*)(ws + o); o += (size_t)3*CC*CC*2;
  unsigned short* Wpk3 = (unsigned short*)(ws + o); o += (size_t)3*CC*CC*2;
  float*          scb  = (float*)         (ws + o); o += (size_t)C2*4;
  float*          shb  = (float*)         (ws + o); o += (size_t)C2*4;

  knnpack_kernel<<<NB*64 + 384, 256, 0, stream>>>(x, knn, Wc2, Wc3, Wpk2, Wpk3);

  conv_all_kernel<<<NB, 1024, 0, stream>>>(x, knn, Wc1, bc1, Wpk2, bc2, Wpk3, bc3, gf);

  bnstats_kernel<<<12, 256, 0, stream>>>(gf, bng, bnb, scb, shb);

  dim3 mgrid(12, 32);
  mlp_gemm_kernel<<<mgrid, 512, 0, stream>>>(gf, W1, b1, scb, shb, 1, gt);
  mlp_gemm_kernel<<<mgrid, 512, 0, stream>>>(gt, W2, b2, nullptr, nullptr, 0, gf);
  mlp_gemm_kernel<<<mgrid, 512, 0, stream>>>(gf, W3, b3, nullptr, nullptr, 0, gt);
  mlp_gemm_kernel<<<mgrid, 512, 0, stream>>>(gt, W4, b4, nullptr, nullptr, 0, gf);
  mlp_gemm_kernel<<<mgrid, 512, 0, stream>>>(gf, W5, b5, nullptr, nullptr, 0, gt);

  final_kernel<<<12, 64, 0, stream>>>(gt, Wo, bo, (float*)d_out);
}

// Round 5
// 319.946 us; speedup vs baseline: 1.1993x; 1.0123x over previous
//
#include <hip/hip_runtime.h>
#include <cstdint>
#include <cmath>

#define NB 256      // graphs (B)
#define MM 256      // nodes per graph
#define NN (NB*MM)  // 65536 nodes
#define KNN 15
#define FIN 7
#define CC 128
#define CCP 152     // padded LDS row stride (shorts): 304B = 76 dwords == 12 (mod 32).
                    // Row stride must be ==0 mod 8 shorts (b128 align), so row starts
                    // are pinned to 4-dword bank residues; 152 is the best of that
                    // family for MFMA A-frag reads (R12-16: 136 gave 4-way, 3.02M).
#define FPAD 28     // layer-1 feat row stride (floats): 112B, 16B-aligned for the
                    // conv1 float4 reads; nn*28 mod 32 spans 8 bank residues
                    // (stride 24 spanned only 4 -> 16-way gather conflicts, R4).
#define C2 768
#define NL 3
#define FINF 3.4e38f

__device__ __forceinline__ float lrelu(float v){ return v > 0.f ? v : 0.01f*v; }

__device__ __forceinline__ unsigned short f2bf(float f){
  unsigned u = __float_as_uint(f);
  return (unsigned short)((u + 0x7FFFu + ((u >> 16) & 1u)) >> 16);
}
__device__ __forceinline__ float bf2f(unsigned short h){
  return __uint_as_float(((unsigned)h) << 16);
}

__device__ __forceinline__ int mbcnt64(unsigned long long m){
  return (int)__builtin_amdgcn_mbcnt_hi((unsigned)(m >> 32),
              __builtin_amdgcn_mbcnt_lo((unsigned)m, 0u));
}

typedef short bf16x8 __attribute__((ext_vector_type(8)));
typedef float f32x4  __attribute__((ext_vector_type(4)));

// ------------------------------------------- kNN + packW (merged dispatch) --
// Radix-select (R9: 143 -> 58 us). Parked: issue/SALU-bound, micro-variants
// neutral (R8) or negative (R4, R15-split). packW (384 trivial blocks) rides
// along in the same grid to save one dispatch gap.
__global__ __launch_bounds__(256) void knnpack_kernel(
    const float* __restrict__ x, int* __restrict__ knn,
    const float* __restrict__ W2src, const float* __restrict__ W3src,
    unsigned short* __restrict__ W2dst, unsigned short* __restrict__ W3dst){
  __shared__ float4 pos[MM];
  __shared__ float  sq[MM];
  __shared__ unsigned skey[4][16];
  __shared__ int      sidx[4][16];

  if (blockIdx.x >= NB*64){
    // ---- packW path: pack W into MFMA B-frag order ----
    int idx = (blockIdx.x - NB*64)*256 + threadIdx.x;
    if (idx < 2*3*CC*CC){
      const float* Wsrc = (idx < 3*CC*CC) ? W2src : W3src;
      unsigned short* Wdst = (idx < 3*CC*CC) ? W2dst : W3dst;
      int e = (idx < 3*CC*CC) ? idx : idx - 3*CC*CC;
      int kg = e >> 7;
      int nn = e & 127;
      int ck = kg >> 5, q = (kg >> 3) & 3, j = kg & 7;
      Wdst[(((ck*4 + q)*CC) + nn)*8 + j] = f2bf(Wsrc[e]);
    }
    return;
  }

  const int g = blockIdx.x >> 6;
  const int t = threadIdx.x;
  const float* xr = x + (size_t)(g*MM + t)*FIN;
  float4 p = make_float4(xr[0], xr[1], xr[2], xr[3]);
  pos[t] = p;
  sq[t]  = p.x*p.x + p.y*p.y + p.z*p.z + p.w*p.w;
  __syncthreads();

  const int i    = (blockIdx.x & 63)*4 + (t >> 6);
  const int wv   = t >> 6;
  const int lane = t & 63;
  const float4 pi = pos[i];
  const float  sqi = sq[i];

  unsigned key[4];
#pragma unroll
  for (int qq=0;qq<4;qq++){
    int j = qq*64 + lane;
    float4 pj = pos[j];
    float dot = pi.x*pj.x + pi.y*pj.y + pi.z*pj.z + pi.w*pj.w;
    float d2  = sqi + sq[j] - 2.f*dot;
    unsigned u = __float_as_uint(d2);
    u = ((int)u < 0) ? ~u : (u ^ 0x80000000u);
    key[qq] = (j == i) ? 0xFFFFFFFFu : u;
  }

  unsigned prefix = 0u;
#pragma unroll
  for (int bit=31; bit>=0; --bit){
    unsigned trial = prefix | (1u << bit);
    int c = __popcll(__ballot(key[0] < trial))
          + __popcll(__ballot(key[1] < trial))
          + __popcll(__ballot(key[2] < trial))
          + __popcll(__ballot(key[3] < trial));
    if (c < KNN) prefix = trial;
  }
  const unsigned K = prefix;

  int c_lt = __popcll(__ballot(key[0] < K)) + __popcll(__ballot(key[1] < K))
           + __popcll(__ballot(key[2] < K)) + __popcll(__ballot(key[3] < K));
  int need = KNN - c_lt;
  bool w[4];
  int eqbase = 0;
#pragma unroll
  for (int qq=0;qq<4;qq++){
    unsigned long long em = __ballot(key[qq] == K);
    int gr = eqbase + mbcnt64(em);
    w[qq] = (key[qq] < K) || ((key[qq] == K) && (gr < need));
    eqbase += __popcll(em);
  }

  int base2 = 0;
#pragma unroll
  for (int qq=0;qq<4;qq++){
    unsigned long long wm = __ballot(w[qq]);
    int rk = mbcnt64(wm);
    if (w[qq]){ skey[wv][base2+rk] = key[qq]; sidx[wv][base2+rk] = qq*64 + lane; }
    base2 += __popcll(wm);
  }
  __builtin_amdgcn_wave_barrier();

  if (lane < KNN){
    unsigned mk = skey[wv][lane]; int mi = sidx[wv][lane];
    int r = 0;
#pragma unroll
    for (int m=0;m<KNN;m++){
      unsigned ok = skey[wv][m]; int oi = sidx[wv][m];
      r += (ok < mk || (ok == mk && oi < mi)) ? 1 : 0;
    }
    knn[(size_t)(g*MM + i)*KNN + r] = g*MM + mi;
  }
}

// ---------------------- exact agg128 arithmetic, LDS->LDS (1024 threads) ----
// R0-verbatim (reads kn from global each call): keeps the transient register
// footprint small enough that acc[2][4] stays in AGPRs (R0/R4: 56-64 VGPR,
// zero spill). R1-R3 lesson: opk register cache + per-iteration MFMA
// interleave pushed the live set to ~110 regs; the allocator is hard-pinned
// at 64 VGPRs on this toolchain (launch_bounds(,4) AND amdgpu_waves_per_eu
// both ignored) -> 174-187 MB phantom spill traffic.
__device__ __forceinline__ void agg_lds(const unsigned short* __restrict__ src,
                                        unsigned short* __restrict__ dst,
                                        const int* __restrict__ kn_graph,
                                        int tid){
  for (int it=0; it<4; ++it){
    int idx = it*1024 + tid;
    int nn  = idx >> 4;
    int c8  = (idx & 15) * 8;
    const int* kn = kn_graph + nn*KNN;
    float s[8];
#pragma unroll
    for (int e=0;e<8;e++) s[e]=0.f;
#pragma unroll
    for (int k=0;k<KNN;k++){
      int loc = kn[k] & (MM-1);
      uint4 r = *(const uint4*)(src + loc*CCP + c8);
      s[0] += __uint_as_float(r.x << 16); s[1] += __uint_as_float(r.x & 0xFFFF0000u);
      s[2] += __uint_as_float(r.y << 16); s[3] += __uint_as_float(r.y & 0xFFFF0000u);
      s[4] += __uint_as_float(r.z << 16); s[5] += __uint_as_float(r.z & 0xFFFF0000u);
      s[6] += __uint_as_float(r.w << 16); s[7] += __uint_as_float(r.w & 0xFFFF0000u);
    }
    const float inv = 1.f/15.f;
    uint4 o;
    o.x = (unsigned)f2bf(s[0]*inv) | ((unsigned)f2bf(s[1]*inv) << 16);
    o.y = (unsigned)f2bf(s[2]*inv) | ((unsigned)f2bf(s[3]*inv) << 16);
    o.z = (unsigned)f2bf(s[4]*inv) | ((unsigned)f2bf(s[5]*inv) << 16);
    o.w = (unsigned)f2bf(s[6]*inv) | ((unsigned)f2bf(s[7]*inv) << 16);
    *(uint4*)(dst + nn*CCP + c8) = o;
  }
}

// 4 consecutive MFMA K-chunks from one A buffer (order-preserving helper)
__device__ __forceinline__ void mfma_seg(const unsigned short* __restrict__ A,
                                         const unsigned short* __restrict__ Wpk,
                                         int ck0, int rows0, int cols0,
                                         int n, int q, f32x4 (&acc)[2][4]){
#pragma unroll
  for (int cki=0; cki<4; cki++){
    const int ck = ck0 + cki;
    const int kc = ck & 3;
    const unsigned short* ab = A + (rows0 + n)*CCP + kc*32 + q*8;
    bf16x8 af[2];
#pragma unroll
    for (int i=0;i<2;i++) af[i] = *(const bf16x8*)(ab + i*16*CCP);
    const unsigned short* wb = Wpk + ((size_t)(ck*4 + q)*CC + cols0 + n)*8;
    bf16x8 bfr[4];
#pragma unroll
    for (int t=0;t<4;t++) bfr[t] = *(const bf16x8*)(wb + t*16*8);
#pragma unroll
    for (int i=0;i<2;i++)
#pragma unroll
      for (int t=0;t<4;t++)
        acc[i][t] = __builtin_amdgcn_mfma_f32_16x16x32_bf16(af[i], bfr[t], acc[i][t], 0, 0, 0);
  }
}

__device__ __forceinline__ void conv_epilogue(const float* __restrict__ bvec,
                                              f32x4 (&acc)[2][4],
                                              unsigned short* __restrict__ dst,
                                              int rows0, int cols0, int n, int q){
  float bv[4];
#pragma unroll
  for (int t=0;t<4;t++) bv[t] = bvec[cols0 + t*16 + n];
#pragma unroll
  for (int i=0;i<2;i++)
#pragma unroll
    for (int t=0;t<4;t++)
#pragma unroll
      for (int r=0;r<4;r++){
        int row = rows0 + i*16 + q*4 + r;
        int col = cols0 + t*16 + n;
        dst[row*CCP + col] = f2bf(lrelu(acc[i][t][r] + bv[t]));
      }
}

// all-wave pool: waves 0-7 sum, waves 8-15 max (same add/max order as the
// original serial version -> bit-exact; doubles pool-phase utilization).
// NOTE: no trailing barrier -- callers rely on: the next phase never reads
// pool's scratch and never writes pool's source buffer before the next
// full barrier.
__device__ __forceinline__ void pool_block(const unsigned short* __restrict__ buf,
                                           float* __restrict__ gf_base,
                                           float (*smean)[CC], float (*smax)[CC],
                                           int tid){
  const int c = tid & 127;
  const int grp = tid >> 7;             // 0..7, wave-uniform
  if (grp < 4){
    float s = 0.f;
    for (int m=grp*64; m<grp*64+64; ++m) s += bf2f(buf[m*CCP + c]);
    smean[grp][c] = s;
  } else {
    const int gg = grp - 4;
    float mx = -FINF;
    for (int m=gg*64; m<gg*64+64; ++m) mx = fmaxf(mx, bf2f(buf[m*CCP + c]));
    smax[gg][c] = mx;
  }
  __syncthreads();
  if (tid < 128){
    gf_base[c] = (smean[0][c] + smean[1][c] + smean[2][c] + smean[3][c]) * (1.f/MM);
  } else if (tid < 256){
    gf_base[CC + c] = fmaxf(fmaxf(smax[0][c], smax[1][c]),
                            fmaxf(smax[2][c], smax[3][c]));
  }
}

// ---------------- conv layers 1+2+3 fully fused (one block per graph) -------
// Layer 1: feat stride 28 (8 bank residues, was 4) and both hop-aggs run on
// all 1024 threads as (node,channel) items -- per-(nn,c) k-ascending sum
// order identical to the old 256-thread version -> bit-exact.
// Layers 2/3: COARSE commingling -- each mfma_seg shares a barrier region
// with the following agg_lds; both only READ the same buffer, agg writes the
// dead one (hazard-checked), MFMA acc order ck0->11 unchanged -> bit-exact.
// This drops 2 barriers and mixes MFMA + VALU/LDS work per region so waves
// at different progress points keep both pipes busy. Helpers are R4-verbatim
// (known to co-compile at 64 VGPR, zero spill); only call order changed.
// LDS: 2 x 76 KB bufs + 4 KB pool scratch = 156 KB -> 1 block/CU.
__global__ __launch_bounds__(1024) void conv_all_kernel(
    const float* __restrict__ x,
    const int* __restrict__ knn,
    const float* __restrict__ Wc1, const float* __restrict__ bc1,
    const unsigned short* __restrict__ Wpk2, const float* __restrict__ b2,
    const unsigned short* __restrict__ Wpk3, const float* __restrict__ b3,
    float* __restrict__ gf){
  __shared__ __align__(16) unsigned short bufh[MM*CCP];   // 77824 B
  __shared__ __align__(16) unsigned short bufa[MM*CCP];   // 77824 B
  __shared__ float smean[4][CC], smax[4][CC];
  const int g   = blockIdx.x;
  const int tid = threadIdx.x;
  const int* kn_graph = knn + (size_t)g*MM*KNN;

  // ================= layer 1 (feat in bufa's space) =================
  {
    float (*feat)[FPAD] = (float (*)[FPAD])bufa;   // 28672 B < bufa
    for (int e=tid; e<MM*FIN; e+=1024){
      int nn = e / FIN, f = e - nn*FIN;
      feat[nn][f] = x[(size_t)g*MM*FIN + e];
    }
    __syncthreads();
    // two hop-aggregations, all 1024 threads over 1792 (nn,c) items
#pragma unroll
    for (int pass=0; pass<2; ++pass){
      for (int it=0; it<2; ++it){
        int e = it*1024 + tid;
        if (e < MM*FIN){
          int nn = e / FIN, c = e - nn*FIN;
          const int* kn = kn_graph + nn*KNN;
          float s = 0.f;
#pragma unroll
          for (int k=0;k<KNN;k++) s += feat[kn[k] & (MM-1)][pass*FIN + c];
          feat[nn][(pass+1)*FIN + c] = s * (1.f/15.f);
        }
      }
      __syncthreads();
    }
    // conv1: 1024 threads, 8 segs x 32 nodes; write h into bufh (CCP layout)
    {
      const int cc_ = tid & 127;
      const int seg = tid >> 7;
      float wcol[3*FIN];
#pragma unroll
      for (int t2=0;t2<3*FIN;t2++) wcol[t2] = Wc1[t2*CC + cc_];
      const float bc = bc1[cc_];
      for (int nn=seg*32; nn<seg*32+32; ++nn){
        float4 f0 = *(const float4*)(&feat[nn][0]);
        float4 f1 = *(const float4*)(&feat[nn][4]);
        float4 f2 = *(const float4*)(&feat[nn][8]);
        float4 f3 = *(const float4*)(&feat[nn][12]);
        float4 f4 = *(const float4*)(&feat[nn][16]);
        float4 f5 = *(const float4*)(&feat[nn][20]);
        float fv[21] = {f0.x,f0.y,f0.z,f0.w, f1.x,f1.y,f1.z,f1.w,
                        f2.x,f2.y,f2.z,f2.w, f3.x,f3.y,f3.z,f3.w,
                        f4.x,f4.y,f4.z,f4.w, f5.x};
        float a1 = bc;
#pragma unroll
        for (int t2=0;t2<3*FIN;t2++) a1 += fv[t2]*wcol[t2];
        bufh[nn*CCP + cc_] = f2bf(lrelu(a1));
      }
    }
    __syncthreads();
    pool_block(bufh, gf + (size_t)g*C2, smean, smax, tid);
    // no barrier: next region reads bufh (read-read with pool partials) and
    // writes only bufa (feat now dead); pool finals touch only smean/smax.
  }

  const int wv   = tid >> 6, lane = tid & 63;
  const int n    = lane & 15, q = lane >> 4;
  const int rows0 = (wv & 7)*32;
  const int cols0 = (wv >> 3)*64;

  f32x4 acc[2][4];

  // ================= layer 2 =================
#pragma unroll
  for (int i=0;i<2;i++)
#pragma unroll
    for (int t=0;t<4;t++) acc[i][t] = (f32x4){0.f,0.f,0.f,0.f};
  // region A: both read bufh; agg writes bufa (dead feat)
  mfma_seg(bufh, Wpk2, 0, rows0, cols0, n, q, acc);   // ck0-3 (h)
  agg_lds(bufh, bufa, kn_graph, tid);                 // a1_2 = agg(h)
  __syncthreads();
  // region B: both read bufa; agg writes bufh (h dead: last read pre-barrier)
  mfma_seg(bufa, Wpk2, 4, rows0, cols0, n, q, acc);   // ck4-7 (a1)
  agg_lds(bufa, bufh, kn_graph, tid);                 // a2_2 = agg(a1)
  __syncthreads();
  // region C: mfma reads bufh; epilogue writes bufa (a1 dead)
  mfma_seg(bufh, Wpk2, 8, rows0, cols0, n, q, acc);   // ck8-11 (a2)
  conv_epilogue(b2, acc, bufa, rows0, cols0, n, q);   // h3 -> bufa (stays in LDS)
  __syncthreads();
  pool_block(bufa, gf + (size_t)g*C2 + 2*CC, smean, smax, tid);
  // no barrier: next region reads bufa (read-read with pool) and writes bufh.

  // ================= layer 3 (h3 = bufa) =================
#pragma unroll
  for (int i=0;i<2;i++)
#pragma unroll
    for (int t=0;t<4;t++) acc[i][t] = (f32x4){0.f,0.f,0.f,0.f};
  mfma_seg(bufa, Wpk3, 0, rows0, cols0, n, q, acc);   // ck0-3 (h3)
  agg_lds(bufa, bufh, kn_graph, tid);                 // a1_3 = agg(h3)
  __syncthreads();
  mfma_seg(bufh, Wpk3, 4, rows0, cols0, n, q, acc);   // ck4-7 (a1_3)
  agg_lds(bufh, bufa, kn_graph, tid);                 // a2_3 = agg(a1_3)
  __syncthreads();
  mfma_seg(bufa, Wpk3, 8, rows0, cols0, n, q, acc);   // ck8-11 (a2_3)
  conv_epilogue(b3, acc, bufh, rows0, cols0, n, q);   // only the pool reads it
  __syncthreads();
  pool_block(bufh, gf + (size_t)g*C2 + 4*CC, smean, smax, tid);
}

// ------------------------------------------------------ batchnorm (stats) ---
__global__ __launch_bounds__(256) void bnstats_kernel(const float* __restrict__ g,
                                                      const float* __restrict__ gamma,
                                                      const float* __restrict__ beta,
                                                      float* __restrict__ scb,
                                                      float* __restrict__ shb){
  __shared__ float ssum[4][64], ssq[4][64];
  const int cl = threadIdx.x & 63, rg = threadIdx.x >> 6;
  const int c  = blockIdx.x*64 + cl;
  float s=0.f, q=0.f;
  for (int r=rg*64; r<rg*64+64; r++){
    float v = g[(size_t)r*C2 + c];
    s += v; q += v*v;
  }
  ssum[rg][cl]=s; ssq[rg][cl]=q;
  __syncthreads();
  if (rg == 0){
    s = ssum[0][cl]+ssum[1][cl]+ssum[2][cl]+ssum[3][cl];
    q = ssq [0][cl]+ssq [1][cl]+ssq [2][cl]+ssq [3][cl];
    float mu  = s * (1.f/NB);
    float var = q * (1.f/NB) - mu*mu;
    float sc  = rsqrtf(var + 1e-5f) * gamma[c];
    scb[c] = sc;
    shb[c] = beta[c] - mu*sc;
  }
}

// -------------------------------------------------- MLP (wave-K-split GEMM) -
__global__ __launch_bounds__(512) void mlp_gemm_kernel(
    const float* __restrict__ A, const float* __restrict__ W,
    const float* __restrict__ bias,
    const float* __restrict__ scb, const float* __restrict__ shb, int affine,
    float* __restrict__ out){
  __shared__ float Ws[8][32][64];   // 64 KB
  __shared__ float At[8][32][10];   // 10 KB
  const int tid  = threadIdx.x;
  const int ks   = tid >> 6, lane = tid & 63;
  const int colq = lane & 15, rp = lane >> 4;
  const int col0 = blockIdx.x * 64;
  const int row0 = blockIdx.y * 8;

  float a00=0.f,a01=0.f,a02=0.f,a03=0.f;
  float a10=0.f,a11=0.f,a12=0.f,a13=0.f;

  for (int kt=0; kt<3; kt++){
    const int kc0 = ks*96 + kt*32;
#pragma unroll
    for (int i=0;i<8;i++){
      int idx = i*256 + lane*4;
      int kr = idx >> 6, cc = idx & 63;
      *(float4*)(&Ws[ks][kr][cc]) =
          *(const float4*)(W + (size_t)(kc0+kr)*C2 + col0 + cc);
    }
    {
      int row = lane >> 3, kq = lane & 7;
      float4 a = *(const float4*)(A + (size_t)(row0+row)*C2 + kc0 + kq*4);
      if (affine){
        float4 s4 = *(const float4*)(scb + kc0 + kq*4);
        float4 h4 = *(const float4*)(shb + kc0 + kq*4);
        a.x = a.x*s4.x + h4.x; a.y = a.y*s4.y + h4.y;
        a.z = a.z*s4.z + h4.z; a.w = a.w*s4.w + h4.w;
      }
      At[ks][kq*4+0][row] = a.x;
      At[ks][kq*4+1][row] = a.y;
      At[ks][kq*4+2][row] = a.z;
      At[ks][kq*4+3][row] = a.w;
    }
    __builtin_amdgcn_wave_barrier();
#pragma unroll 8
    for (int kk=0;kk<32;kk++){
      float4 w = *(const float4*)(&Ws[ks][kk][colq*4]);
      float b0 = At[ks][kk][rp*2+0];
      float b1 = At[ks][kk][rp*2+1];
      a00 += b0*w.x; a01 += b0*w.y; a02 += b0*w.z; a03 += b0*w.w;
      a10 += b1*w.x; a11 += b1*w.y; a12 += b1*w.z; a13 += b1*w.w;
    }
    __builtin_amdgcn_wave_barrier();
  }

  if (ks > 0){
    float* part = &Ws[ks][0][0];
    *(float4*)(part + (rp*2+0)*64 + colq*4) = make_float4(a00,a01,a02,a03);
    *(float4*)(part + (rp*2+1)*64 + colq*4) = make_float4(a10,a11,a12,a13);
  }
  __syncthreads();
  if (ks == 0){
    float4 bv = *(const float4*)(bias + col0 + colq*4);
    float accr[2][4] = {{a00,a01,a02,a03},{a10,a11,a12,a13}};
#pragma unroll
    for (int r=0;r<2;r++){
      int off = (rp*2+r)*64 + colq*4;
      float sx = accr[r][0], sy = accr[r][1], sz = accr[r][2], sw = accr[r][3];
#pragma unroll
      for (int pw=1; pw<8; pw++){
        float4 pp = *(const float4*)(&Ws[pw][0][0] + off);
        sx += pp.x; sy += pp.y; sz += pp.z; sw += pp.w;
      }
      float4 o;
      o.x = lrelu(sx + bv.x);
      o.y = lrelu(sy + bv.y);
      o.z = lrelu(sz + bv.z);
      o.w = lrelu(sw + bv.w);
      *(float4*)(out + (size_t)(row0 + rp*2 + r)*C2 + col0 + colq*4) = o;
    }
  }
}

// ------------------------------------------------------------- final layer --
__global__ __launch_bounds__(64) void final_kernel(const float* __restrict__ g,
                                                   const float* __restrict__ Wo,
                                                   const float* __restrict__ bo,
                                                   float* __restrict__ out){
  int i = blockIdx.x*64 + threadIdx.x;
  if (i >= NB*NL) return;
  int r = i / NL, c = i - r*NL;
  const float* gr = g + (size_t)r*C2;
  float acc = bo[c];
  for (int k=0;k<C2;k++) acc += gr[k]*Wo[k*NL + c];
  if (c < 2) acc = tanhf(acc);
  out[i] = acc;
}

// ------------------------------------------------------------------ launch --
extern "C" void kernel_launch(void* const* d_in, const int* in_sizes, int n_in,
                              void* d_out, int out_size, void* d_ws, size_t ws_size,
                              hipStream_t stream){
  const float* x   = (const float*)d_in[0];
  const float* Wc1 = (const float*)d_in[1];
  const float* bc1 = (const float*)d_in[2];
  const float* Wc2 = (const float*)d_in[3];
  const float* bc2 = (const float*)d_in[4];
  const float* Wc3 = (const float*)d_in[5];
  const float* bc3 = (const float*)d_in[6];
  const float* bng = (const float*)d_in[7];
  const float* bnb = (const float*)d_in[8];
  const float* W1  = (const float*)d_in[9];
  const float* b1  = (const float*)d_in[10];
  const float* W2  = (const float*)d_in[11];
  const float* b2  = (const float*)d_in[12];
  const float* W3  = (const float*)d_in[13];
  const float* b3  = (const float*)d_in[14];
  const float* W4  = (const float*)d_in[15];
  const float* b4  = (const float*)d_in[16];
  const float* W5  = (const float*)d_in[17];
  const float* b5  = (const float*)d_in[18];
  const float* Wo  = (const float*)d_in[19];
  const float* bo  = (const float*)d_in[20];

  char* ws = (char*)d_ws;
  size_t o = 0;
  int*            knn  = (int*)           (ws + o); o += (size_t)NN*KNN*4;
  float*          gf   = (float*)         (ws + o); o += (size_t)NB*C2*4;
  float*          gt   = (float*)         (ws + o); o += (size_t)NB*C2*4;
  unsigned short* Wpk2 = (unsigned short*)(ws + o); o += (size_t)3*CC*CC*2;
  unsigned short* Wpk3 = (unsigned short*)(ws + o); o += (size_t)3*CC*CC*2;
  float*          scb  = (float*)         (ws + o); o += (size_t)C2*4;
  float*          shb  = (float*)         (ws + o); o += (size_t)C2*4;

  knnpack_kernel<<<NB*64 + 384, 256, 0, stream>>>(x, knn, Wc2, Wc3, Wpk2, Wpk3);

  conv_all_kernel<<<NB, 1024, 0, stream>>>(x, knn, Wc1, bc1, Wpk2, bc2, Wpk3, bc3, gf);

  bnstats_kernel<<<12, 256, 0, stream>>>(gf, bng, bnb, scb, shb);

  dim3 mgrid(12, 32);
  mlp_gemm_kernel<<<mgrid, 512, 0, stream>>>(gf, W1, b1, scb, shb, 1, gt);
  mlp_gemm_kernel<<<mgrid, 512, 0, stream>>>(gt, W2, b2, nullptr, nullptr, 0, gf);
  mlp_gemm_kernel<<<mgrid, 512, 0, stream>>>(gf, W3, b3, nullptr, nullptr, 0, gt);
  mlp_gemm_kernel<<<mgrid, 512, 0, stream>>>(gt, W4, b4, nullptr, nullptr, 0, gf);
  mlp_gemm_kernel<<<mgrid, 512, 0, stream>>>(gf, W5, b5, nullptr, nullptr, 0, gt);

  final_kernel<<<12, 64, 0, stream>>>(gt, Wo, bo, (float*)d_out);
}